// Round 2
// baseline (383.441 us; speedup 1.0000x reference)
//
#include <hip/hip_runtime.h>
#include <hip/hip_bf16.h>

// ComplexAttention: B=2, L=2048, D=1024, H=16, HD=64, SCALE=0.125
// Pipeline: pack(x,w) -> bf16 GEMM (QKV: 256x256 8-phase counted-vmcnt; Q pre-scaled,
//           V stored transposed) -> flash attn (8-wave paired q-tiles) -> bf16 GEMM 128x128.
// All LDS tiles staged via global_load_lds(16B) with XOR-16B-chunk swizzle
// (chunk' = chunk ^ (row&7)) folded into the GLOBAL address so LDS stays
// contiguous (wave-uniform base + lane*16 contract) yet frag reads are ~conflict-free.

using f32x4  = __attribute__((ext_vector_type(4))) float;
using short8 = __attribute__((ext_vector_type(8))) short;   // 8 bf16 = 4 VGPRs (MFMA A/B frag)
using bf16_t = __hip_bfloat16;

#define AS1 __attribute__((address_space(1)))
#define AS3 __attribute__((address_space(3)))

__device__ __forceinline__ void gload_lds16(const bf16_t* g, bf16_t* l) {
  __builtin_amdgcn_global_load_lds((const AS1 unsigned int*)g, (AS3 unsigned int*)l, 16, 0, 0);
}

__device__ __forceinline__ unsigned short bfbits(float f) {
  union { bf16_t h; unsigned short u; } c; c.h = __float2bfloat16(f); return c.u;
}

// ---------------------------------------------------------------- pack kernels
__global__ void pack_x_k(const float* __restrict__ xr, const float* __restrict__ xi,
                         bf16_t* __restrict__ out) {
  const int total4 = 4096 * 2048 / 4;
  for (int idx = blockIdx.x * blockDim.x + threadIdx.x; idx < total4;
       idx += gridDim.x * blockDim.x) {
    int m = idx >> 9, k = (idx & 511) * 4;
    const float* src = (k < 1024) ? (xr + (size_t)m * 1024 + k)
                                  : (xi + (size_t)m * 1024 + (k - 1024));
    float4 v = *(const float4*)src;
    unsigned int lo = (unsigned)bfbits(v.x) | ((unsigned)bfbits(v.y) << 16);
    unsigned int hi = (unsigned)bfbits(v.z) | ((unsigned)bfbits(v.w) << 16);
    *(uint2*)(out + (size_t)idx * 4) = make_uint2(lo, hi);
  }
}

__global__ void pack_wqkv_k(const float* __restrict__ wqr, const float* __restrict__ wqi,
                            const float* __restrict__ wkr, const float* __restrict__ wki,
                            const float* __restrict__ wvr, const float* __restrict__ wvi,
                            bf16_t* __restrict__ out) {
  const int total4 = 6144 * 2048 / 4;
  for (int idx = blockIdx.x * blockDim.x + threadIdx.x; idx < total4;
       idx += gridDim.x * blockDim.x) {
    int row = idx >> 9, k = (idx & 511) * 4;
    int sec = row >> 10, r1 = row & 1023;
    bool lowk = (k < 1024);
    int kk = lowk ? k : (k - 1024);
    const float* base = wqr; float sg = 1.f;
    switch (sec) {
      case 0: base = lowk ? wqr : wqi; sg = lowk ? 1.f : -1.f; break;
      case 1: base = lowk ? wqi : wqr; break;
      case 2: base = lowk ? wkr : wki; sg = lowk ? 1.f : -1.f; break;
      case 3: base = lowk ? wki : wkr; break;
      case 4: base = lowk ? wvr : wvi; sg = lowk ? 1.f : -1.f; break;
      case 5: base = lowk ? wvi : wvr; break;
    }
    float4 v = *(const float4*)(base + (size_t)r1 * 1024 + kk);
    unsigned int lo = (unsigned)bfbits(v.x * sg) | ((unsigned)bfbits(v.y * sg) << 16);
    unsigned int hi = (unsigned)bfbits(v.z * sg) | ((unsigned)bfbits(v.w * sg) << 16);
    *(uint2*)(out + (size_t)idx * 4) = make_uint2(lo, hi);
  }
}

__global__ void pack_wo_k(const float* __restrict__ wor, const float* __restrict__ woi,
                          bf16_t* __restrict__ out) {
  const int total4 = 2048 * 2048 / 4;
  for (int idx = blockIdx.x * blockDim.x + threadIdx.x; idx < total4;
       idx += gridDim.x * blockDim.x) {
    int row = idx >> 9, k = (idx & 511) * 4;
    int sec = row >> 10, r1 = row & 1023;
    bool lowk = (k < 1024);
    int kk = lowk ? k : (k - 1024);
    const float* base; float sg = 1.f;
    if (sec == 0) { base = lowk ? wor : woi; sg = lowk ? 1.f : -1.f; }
    else          { base = lowk ? woi : wor; }
    float4 v = *(const float4*)(base + (size_t)r1 * 1024 + kk);
    unsigned int lo = (unsigned)bfbits(v.x * sg) | ((unsigned)bfbits(v.y * sg) << 16);
    unsigned int hi = (unsigned)bfbits(v.z * sg) | ((unsigned)bfbits(v.w * sg) << 16);
    *(uint2*)(out + (size_t)idx * 4) = make_uint2(lo, hi);
  }
}

// ---------------------------------------------------------------- GEMM core 128x128 (gemm_out)
__device__ __forceinline__ void gemm_core(const bf16_t* __restrict__ A,
                                          const bf16_t* __restrict__ W,
                                          int m0, int n0, f32x4 (&acc)[4][4]) {
  __shared__ __align__(16) bf16_t sA[128 * 64];
  __shared__ __align__(16) bf16_t sB[128 * 64];
  const int tid = threadIdx.x;
  const int lane = tid & 63, w = tid >> 6;
  const int wr = w >> 1, wc = w & 1;
  const int quad = lane >> 4, m16 = lane & 15;
  const int srow = w * 32 + (lane >> 3);                 // + i*8
  const int gcol = (((lane & 7) ^ (lane >> 3)) * 8);     // global k-offset within tile
  const int swz7 = m16 & 7;                              // frag-read swizzle
  for (int k0 = 0; k0 < 2048; k0 += 64) {
    __syncthreads();
#pragma unroll
    for (int i = 0; i < 4; ++i) {
      gload_lds16(A + (size_t)(m0 + srow + i * 8) * 2048 + k0 + gcol,
                  sA + (size_t)(w * 32 + i * 8) * 64 + lane * 8);
      gload_lds16(W + (size_t)(n0 + srow + i * 8) * 2048 + k0 + gcol,
                  sB + (size_t)(w * 32 + i * 8) * 64 + lane * 8);
    }
    __syncthreads();
#pragma unroll
    for (int kk = 0; kk < 2; ++kk) {
      short8 af[4], bf[4];
#pragma unroll
      for (int i = 0; i < 4; ++i)
        af[i] = *(const short8*)(sA + (wr * 64 + i * 16 + m16) * 64 +
                                 ((kk * 4 + quad) ^ swz7) * 8);
#pragma unroll
      for (int j = 0; j < 4; ++j)
        bf[j] = *(const short8*)(sB + (wc * 64 + j * 16 + m16) * 64 +
                                 ((kk * 4 + quad) ^ swz7) * 8);
#pragma unroll
      for (int i = 0; i < 4; ++i)
#pragma unroll
        for (int j = 0; j < 4; ++j)
          acc[i][j] = __builtin_amdgcn_mfma_f32_16x16x32_bf16(af[i], bf[j], acc[i][j], 0, 0, 0);
    }
  }
}

// ---------------------------------------------------------------- QKV GEMM: 256x256, 8-phase
// C[m,n] = sum_k A[m,k]*W[n,k]; A: 4096x2048, W: 6144x2048. 8 waves (2M x 4N),
// per-wave 128x64 output = acc[8][4]. BK=64, double-buffered LDS (128 KiB).
// Phase nf (0..3): ds_read frags (A all 16 at nf=0; B 2/phase), stage one 128-row
// half-tile, s_barrier, setprio(1), 16 MFMA, setprio(0), s_barrier.
// Stage schedule: ph0 B0(t+1)->buf q, ph1 B1(t+1)->q, ph2 A0(t+2)->buf p (A slots
// die after ph0), ph3 A1(t+2)->p. Boundary wait vmcnt(4): per-wave issue order puts
// exactly tile(t+1)'s 8 loads oldest; A(t+2)'s 4 loads stay in flight. Drain only at
// t==NT-2. cols 0..4095 -> qk (Qr|Qi|Kr|Ki, Q pre-scaled); 4096..6143 -> V transposed.
__global__ __launch_bounds__(512, 2) void gemm_qkv_k(const bf16_t* __restrict__ A,
                                                     const bf16_t* __restrict__ W,
                                                     bf16_t* __restrict__ qk,
                                                     bf16_t* __restrict__ vt) {
  __shared__ __align__(16) bf16_t sA[2][256 * 64];  // 64 KB
  __shared__ __align__(16) bf16_t sB[2][256 * 64];  // 64 KB
  const int tid = threadIdx.x, lane = tid & 63, w = tid >> 6;
  const int wm = w >> 2, wn = w & 3;
  const int quad = lane >> 4, m16 = lane & 15;
  const int swz7 = m16 & 7;
  const int m0 = blockIdx.x * 256, n0 = blockIdx.y * 256;
  const int NT = 32;

  // staging geometry per 128-row half-tile: wave w instr i covers rows w*16+i*8+(lane>>3)
  const int srow = w * 16 + (lane >> 3);
  const int gcol = (((lane & 7) ^ (lane >> 3)) * 8);

  f32x4 acc[8][4] = {};

  auto stageA = [&](int buf, int half, int k0) {
#pragma unroll
    for (int i = 0; i < 2; ++i)
      gload_lds16(A + (size_t)(m0 + half * 128 + srow + i * 8) * 2048 + k0 + gcol,
                  &sA[buf][(size_t)(half * 128 + w * 16 + i * 8) * 64] + lane * 8);
  };
  auto stageB = [&](int buf, int half, int k0) {
#pragma unroll
    for (int i = 0; i < 2; ++i)
      gload_lds16(W + (size_t)(n0 + half * 128 + srow + i * 8) * 2048 + k0 + gcol,
                  &sB[buf][(size_t)(half * 128 + w * 16 + i * 8) * 64] + lane * 8);
  };

  // prologue: tile0 (A,B) + tile1 A halves. In flight after wait: A(1) = 4 loads.
  stageA(0, 0, 0); stageA(0, 1, 0);
  stageB(0, 0, 0); stageB(0, 1, 0);
  stageA(1, 0, 64); stageA(1, 1, 64);
  asm volatile("s_waitcnt vmcnt(4)" ::: "memory");
  __builtin_amdgcn_s_barrier();

  for (int t = 0; t < NT; ++t) {
    const int p = t & 1, q = p ^ 1;
    const bf16_t* sAp = sA[p];
    const bf16_t* sBp = sB[p];
    short8 af[8][2];
#pragma unroll
    for (int nf = 0; nf < 4; ++nf) {
      if (nf == 0) {
#pragma unroll
        for (int mf = 0; mf < 8; ++mf)
#pragma unroll
          for (int kk = 0; kk < 2; ++kk)
            af[mf][kk] = *(const short8*)(sAp + (wm * 128 + mf * 16 + m16) * 64 +
                                          ((kk * 4 + quad) ^ swz7) * 8);
      }
      short8 bf[2];
#pragma unroll
      for (int kk = 0; kk < 2; ++kk)
        bf[kk] = *(const short8*)(sBp + (wn * 64 + nf * 16 + m16) * 64 +
                                  ((kk * 4 + quad) ^ swz7) * 8);
      // stage one half-tile (guards uniform across block)
      if (nf == 0)      { if (t + 1 < NT) stageB(q, 0, (t + 1) * 64); }
      else if (nf == 1) { if (t + 1 < NT) stageB(q, 1, (t + 1) * 64); }
      else if (nf == 2) { if (t + 2 < NT) stageA(p, 0, (t + 2) * 64); }
      else              { if (t + 2 < NT) stageA(p, 1, (t + 2) * 64); }
      asm volatile("" ::: "memory");
      __builtin_amdgcn_s_barrier();
      __builtin_amdgcn_s_setprio(1);
#pragma unroll
      for (int mf = 0; mf < 8; ++mf)
#pragma unroll
        for (int kk = 0; kk < 2; ++kk)
          acc[mf][nf] = __builtin_amdgcn_mfma_f32_16x16x32_bf16(af[mf][kk], bf[kk],
                                                                acc[mf][nf], 0, 0, 0);
      __builtin_amdgcn_s_setprio(0);
      asm volatile("" ::: "memory");
      if (nf == 3) {
        if (t == NT - 2)      asm volatile("s_waitcnt vmcnt(0)" ::: "memory");
        else if (t < NT - 2)  asm volatile("s_waitcnt vmcnt(4)" ::: "memory");
      }
      __builtin_amdgcn_s_barrier();
    }
  }

  // epilogue
#pragma unroll
  for (int mf = 0; mf < 8; ++mf) {
    const int rowb = m0 + wm * 128 + mf * 16 + quad * 4;   // C/D row = quad*4 + reg
#pragma unroll
    for (int nf = 0; nf < 4; ++nf) {
      const int col = n0 + wn * 64 + nf * 16 + m16;        // C/D col = lane&15
      if (col < 4096) {
        const float sc = (col < 2048) ? 0.125f : 1.f;      // pre-scale Q by SCALE
#pragma unroll
        for (int r = 0; r < 4; ++r)
          qk[(size_t)(rowb + r) * 4096 + col] = __float2bfloat16(acc[mf][nf][r] * sc);
      } else {
        const int vcol = col - 4096;
        const int ri = vcol >> 10, dfeat = vcol & 1023;
        const int b = rowb >> 11, seq = rowb & 2047;
        const size_t vrow = (size_t)(b * 2048 + (dfeat >> 6) * 128 + ri * 64 + (dfeat & 63));
        unsigned int lo = (unsigned)bfbits(acc[mf][nf][0]) | ((unsigned)bfbits(acc[mf][nf][1]) << 16);
        unsigned int hi = (unsigned)bfbits(acc[mf][nf][2]) | ((unsigned)bfbits(acc[mf][nf][3]) << 16);
        *(uint2*)(vt + vrow * 2048 + seq) = make_uint2(lo, hi);
      }
    }
  }
}

// Output GEMM: N=2048 ([yr|yi]), fp32 out + bias. 128x128 core.
__global__ __launch_bounds__(256) void gemm_out_k(const bf16_t* __restrict__ A,
                                                  const bf16_t* __restrict__ W,
                                                  const float* __restrict__ bor,
                                                  const float* __restrict__ boi,
                                                  float* __restrict__ out) {
  f32x4 acc[4][4] = {};
  const int m0 = blockIdx.x * 128, n0 = blockIdx.y * 128;
  gemm_core(A, W, m0, n0, acc);
  const int lane = threadIdx.x & 63, w = threadIdx.x >> 6;
  const int wr = w >> 1, wc = w & 1, quad = lane >> 4, m16 = lane & 15;
#pragma unroll
  for (int i = 0; i < 4; ++i) {
    const int rowb = m0 + wr * 64 + i * 16 + quad * 4;
#pragma unroll
    for (int j = 0; j < 4; ++j) {
      const int col = n0 + wc * 64 + j * 16 + m16;
      float bias; float* op;
      if (col < 1024) { bias = bor[col]; op = out + col; }
      else            { bias = boi[col - 1024]; op = out + 4194304 + (col - 1024); }
#pragma unroll
      for (int r = 0; r < 4; ++r)
        op[(size_t)(rowb + r) * 1024] = acc[i][j][r] + bias;
    }
  }
}

// ---------------------------------------------------------------- flash attention
// grid (16, B*H), 512 threads = 8 waves. Waves 0-3 own 16 q-rows each of subtile
// A = x*64..; waves 4-7 own subtile B = (31-x)*64.. . Shared staged K/V tile,
// joint k-loop over nT=32-x tiles, BK=64. Fixed-max softmax, ones-row-MFMA row sums.
__global__ __launch_bounds__(512, 4) void attn_k(const bf16_t* __restrict__ qk,
                                                 const bf16_t* __restrict__ vt,
                                                 bf16_t* __restrict__ acat) {
  __shared__ __align__(16) bf16_t sK[64 * 128];       // 16 KB
  __shared__ __align__(16) bf16_t sV[144 * 64];       // 18 KB (rows 128..143: ones/zeros)
  __shared__ __align__(16) bf16_t sP[8][16 * 72];     // 18 KB (one slab per wave)
  const int tid = threadIdx.x, lane = tid & 63, w = tid >> 6;
  const int wq = w & 3, sub = w >> 2;                 // sub 0 = subtile A, 1 = subtile B
  const int quad = lane >> 4, m16 = lane & 15;
  const int x = blockIdx.x, bh = blockIdx.y, b = bh >> 4, h = bh & 15;
  const size_t qkrow0 = (size_t)b * 2048;
  const int qA = x * 64, qB = (31 - x) * 64;
  const int nT = 32 - x;
  const int swz7 = m16 & 7;
  const int qbase = (sub ? qB : qA) + wq * 16;

  // preset sV rows 128..143: row 128 = ones, rest zeros (constant rows: swizzle-invariant)
  if (tid < 256) {
    const int rr = tid >> 4, cb = (tid & 15) * 4;
    const bf16_t v = __float2bfloat16(rr == 0 ? 1.f : 0.f);
#pragma unroll
    for (int i = 0; i < 4; ++i) sV[(128 + rr) * 64 + cb + i] = v;
  }

  // Q fragments for this wave's 16 rows (A-operand: m=lane&15, k=quad*8+j), d-chunks of 32
  short8 qf[4];
  {
    const bf16_t* qa = qk + (qkrow0 + qbase + m16) * 4096;
#pragma unroll
    for (int kk = 0; kk < 4; ++kk) {
      const int col = (kk >> 1) * 1024 + h * 64 + (kk & 1) * 32 + quad * 8;
      qf[kk] = *(const short8*)(qa + col);
    }
  }
  f32x4 o[9];
#pragma unroll
  for (int j = 0; j < 9; ++j) o[j] = (f32x4){0.f, 0.f, 0.f, 0.f};

  const int qrow = qbase + quad * 4;

  // staging geometry
  const int kl4 = lane >> 4, kl15 = lane & 15;   // K tile: 4 rows/instr (256 B rows)
  const int vl3 = lane >> 3;                     // V tile: 8 rows/instr (128 B rows)
  const int vg7 = ((lane & 7) ^ vl3) * 8;

  for (int t = 0; t < nT; ++t) {
    const int k0 = t * 64;
    __syncthreads();
    // stage K: 64 rows x 128 elem (Kr|Ki of head h); wave w covers rows w*8+i*4+kl4
#pragma unroll
    for (int i = 0; i < 2; ++i) {
      const int row = w * 8 + i * 4 + kl4;
      const int g = kl15 ^ (row & 7);            // low-3 XOR; bit3 of kl15 preserved
      const int col = 2048 + (g >> 3) * 1024 + h * 64 + (g & 7) * 8;
      gload_lds16(qk + (qkrow0 + k0 + row) * 4096 + col,
                  sK + (size_t)(w * 8 + i * 4) * 128 + lane * 8);
    }
    // stage V^T: 128 d-rows x 64 k; wave w covers rows w*16+i*8+vl3
#pragma unroll
    for (int i = 0; i < 2; ++i) {
      const int row = w * 16 + i * 8 + vl3;
      gload_lds16(vt + ((size_t)bh * 128 + row) * 2048 + k0 + vg7,
                  sV + (size_t)(w * 16 + i * 8) * 64 + lane * 8);
    }
    __syncthreads();

    const bool act = sub ? true : (t <= x);      // B-waves always active
    if (act) {
      const bool dg = sub ? (t == nT - 1) : (t == x);

      // ---- S = Qs·K^T (16 q-rows x 64 k)
      f32x4 sv[4];
#pragma unroll
      for (int jt = 0; jt < 4; ++jt) {
        f32x4 a = (f32x4){0.f, 0.f, 0.f, 0.f};
#pragma unroll
        for (int kk = 0; kk < 4; ++kk) {
          short8 kf = *(const short8*)(sK + (jt * 16 + m16) * 128 +
                                       ((kk * 4 + quad) ^ swz7) * 8);
          a = __builtin_amdgcn_mfma_f32_16x16x32_bf16(qf[kk], kf, a, 0, 0, 0);
        }
        sv[jt] = a;
      }

      // ---- fixed-max softmax: P = exp(S), C-layout -> A-layout via per-wave sP
      bf16_t* pw = sP[w];
#pragma unroll
      for (int jt = 0; jt < 4; ++jt)
#pragma unroll
        for (int r = 0; r < 4; ++r) {
          float s = sv[jt][r];
          if (dg && (k0 + jt * 16 + m16 > qrow + r)) s = -1e30f;
          pw[(quad * 4 + r) * 72 + jt * 16 + m16] = __float2bfloat16(__expf(s));
        }
      asm volatile("s_waitcnt lgkmcnt(0)" ::: "memory");  // own-wave P write->read

      // ---- O += P·V (j=8 = ones-row -> row sums l)
#pragma unroll
      for (int kc = 0; kc < 2; ++kc) {
        short8 p = *(const short8*)(pw + m16 * 72 + kc * 32 + quad * 8);
#pragma unroll
        for (int j = 0; j < 9; ++j) {
          short8 vf = *(const short8*)(sV + (j * 16 + m16) * 64 +
                                       ((kc * 4 + quad) ^ swz7) * 8);
          o[j] = __builtin_amdgcn_mfma_f32_16x16x32_bf16(p, vf, o[j], 0, 0, 0);
        }
      }
    }
  }

  // ---- epilogue: l broadcast from lane (quad*16), normalize, write [B,L,2048]=[out_r|out_i]
  float inv[4];
#pragma unroll
  for (int r = 0; r < 4; ++r)
    inv[r] = 1.f / __shfl(o[8][r], lane & 48);
#pragma unroll
  for (int j = 0; j < 8; ++j) {
    const int d = j * 16 + m16;
    const int col = (d < 64) ? (h * 64 + d) : (1024 + h * 64 + (d - 64));
#pragma unroll
    for (int r = 0; r < 4; ++r)
      acat[((size_t)b * 2048 + qrow + r) * 2048 + col] = __float2bfloat16(o[j][r] * inv[r]);
  }
}

// ---------------------------------------------------------------- launch
extern "C" void kernel_launch(void* const* d_in, const int* in_sizes, int n_in,
                              void* d_out, int out_size, void* d_ws, size_t ws_size,
                              hipStream_t stream) {
  const float* xr  = (const float*)d_in[0];
  const float* xi  = (const float*)d_in[1];
  const float* wqr = (const float*)d_in[2];
  const float* wqi = (const float*)d_in[3];
  const float* wkr = (const float*)d_in[4];
  const float* wki = (const float*)d_in[5];
  const float* wvr = (const float*)d_in[6];
  const float* wvi = (const float*)d_in[7];
  const float* wor = (const float*)d_in[8];
  const float* woi = (const float*)d_in[9];
  const float* bor = (const float*)d_in[10];
  const float* boi = (const float*)d_in[11];
  float* out = (float*)d_out;

  char* ws = (char*)d_ws;
  bf16_t* Xcat = (bf16_t*)(ws);                   // 4096x2048   16 MB
  bf16_t* Wqkv = (bf16_t*)(ws + 16777216ull);     // 6144x2048   24 MB
  bf16_t* QKb  = (bf16_t*)(ws + 41943040ull);     // 4096x4096   32 MB
  bf16_t* Vt   = (bf16_t*)(ws + 75497472ull);     // 4096x2048   16 MB (V transposed)
  bf16_t* Acat = (bf16_t*)(ws + 92274688ull);     // 4096x2048   16 MB
  bf16_t* Wo   = (bf16_t*)(ws + 109051904ull);    // 2048x2048    8 MB

  pack_x_k<<<2048, 256, 0, stream>>>(xr, xi, Xcat);
  pack_wqkv_k<<<2048, 256, 0, stream>>>(wqr, wqi, wkr, wki, wvr, wvi, Wqkv);
  pack_wo_k<<<1024, 256, 0, stream>>>(wor, woi, Wo);
  gemm_qkv_k<<<dim3(16, 24), 512, 0, stream>>>(Xcat, Wqkv, QKb, Vt);
  attn_k<<<dim3(16, 32), 512, 0, stream>>>(QKb, Vt, Acat);
  gemm_out_k<<<dim3(32, 16), 256, 0, stream>>>(Acat, Wo, bor, boi, out);
}

// Round 3
// 356.760 us; speedup vs baseline: 1.0748x; 1.0748x over previous
//
#include <hip/hip_runtime.h>
#include <hip/hip_bf16.h>

// ComplexAttention: B=2, L=2048, D=1024, H=16, HD=64, SCALE=0.125
// Pipeline: pack(x,w) -> bf16 GEMM (QKV: 256x192 tile, 4-phase balanced, counted vmcnt;
//           Q pre-scaled, V stored transposed) -> flash attn (8-wave paired q-tiles)
//           -> bf16 GEMM 128x128.
// All LDS tiles staged via global_load_lds(16B) with XOR-16B-chunk swizzle
// (chunk' = chunk ^ (row&7)) folded into the GLOBAL address so LDS stays
// contiguous (wave-uniform base + lane*16 contract) yet frag reads are ~conflict-free.

using f32x4  = __attribute__((ext_vector_type(4))) float;
using short8 = __attribute__((ext_vector_type(8))) short;   // 8 bf16 = 4 VGPRs (MFMA A/B frag)
using bf16_t = __hip_bfloat16;

#define AS1 __attribute__((address_space(1)))
#define AS3 __attribute__((address_space(3)))

__device__ __forceinline__ void gload_lds16(const bf16_t* g, bf16_t* l) {
  __builtin_amdgcn_global_load_lds((const AS1 unsigned int*)g, (AS3 unsigned int*)l, 16, 0, 0);
}

__device__ __forceinline__ unsigned short bfbits(float f) {
  union { bf16_t h; unsigned short u; } c; c.h = __float2bfloat16(f); return c.u;
}

// ---------------------------------------------------------------- pack kernels
__global__ void pack_x_k(const float* __restrict__ xr, const float* __restrict__ xi,
                         bf16_t* __restrict__ out) {
  const int total4 = 4096 * 2048 / 4;
  for (int idx = blockIdx.x * blockDim.x + threadIdx.x; idx < total4;
       idx += gridDim.x * blockDim.x) {
    int m = idx >> 9, k = (idx & 511) * 4;
    const float* src = (k < 1024) ? (xr + (size_t)m * 1024 + k)
                                  : (xi + (size_t)m * 1024 + (k - 1024));
    float4 v = *(const float4*)src;
    unsigned int lo = (unsigned)bfbits(v.x) | ((unsigned)bfbits(v.y) << 16);
    unsigned int hi = (unsigned)bfbits(v.z) | ((unsigned)bfbits(v.w) << 16);
    *(uint2*)(out + (size_t)idx * 4) = make_uint2(lo, hi);
  }
}

__global__ void pack_wqkv_k(const float* __restrict__ wqr, const float* __restrict__ wqi,
                            const float* __restrict__ wkr, const float* __restrict__ wki,
                            const float* __restrict__ wvr, const float* __restrict__ wvi,
                            bf16_t* __restrict__ out) {
  const int total4 = 6144 * 2048 / 4;
  for (int idx = blockIdx.x * blockDim.x + threadIdx.x; idx < total4;
       idx += gridDim.x * blockDim.x) {
    int row = idx >> 9, k = (idx & 511) * 4;
    int sec = row >> 10, r1 = row & 1023;
    bool lowk = (k < 1024);
    int kk = lowk ? k : (k - 1024);
    const float* base = wqr; float sg = 1.f;
    switch (sec) {
      case 0: base = lowk ? wqr : wqi; sg = lowk ? 1.f : -1.f; break;
      case 1: base = lowk ? wqi : wqr; break;
      case 2: base = lowk ? wkr : wki; sg = lowk ? 1.f : -1.f; break;
      case 3: base = lowk ? wki : wkr; break;
      case 4: base = lowk ? wvr : wvi; sg = lowk ? 1.f : -1.f; break;
      case 5: base = lowk ? wvi : wvr; break;
    }
    float4 v = *(const float4*)(base + (size_t)r1 * 1024 + kk);
    unsigned int lo = (unsigned)bfbits(v.x * sg) | ((unsigned)bfbits(v.y * sg) << 16);
    unsigned int hi = (unsigned)bfbits(v.z * sg) | ((unsigned)bfbits(v.w * sg) << 16);
    *(uint2*)(out + (size_t)idx * 4) = make_uint2(lo, hi);
  }
}

__global__ void pack_wo_k(const float* __restrict__ wor, const float* __restrict__ woi,
                          bf16_t* __restrict__ out) {
  const int total4 = 2048 * 2048 / 4;
  for (int idx = blockIdx.x * blockDim.x + threadIdx.x; idx < total4;
       idx += gridDim.x * blockDim.x) {
    int row = idx >> 9, k = (idx & 511) * 4;
    int sec = row >> 10, r1 = row & 1023;
    bool lowk = (k < 1024);
    int kk = lowk ? k : (k - 1024);
    const float* base; float sg = 1.f;
    if (sec == 0) { base = lowk ? wor : woi; sg = lowk ? 1.f : -1.f; }
    else          { base = lowk ? woi : wor; }
    float4 v = *(const float4*)(base + (size_t)r1 * 1024 + kk);
    unsigned int lo = (unsigned)bfbits(v.x * sg) | ((unsigned)bfbits(v.y * sg) << 16);
    unsigned int hi = (unsigned)bfbits(v.z * sg) | ((unsigned)bfbits(v.w * sg) << 16);
    *(uint2*)(out + (size_t)idx * 4) = make_uint2(lo, hi);
  }
}

// ---------------------------------------------------------------- GEMM core 128x128 (gemm_out)
__device__ __forceinline__ void gemm_core(const bf16_t* __restrict__ A,
                                          const bf16_t* __restrict__ W,
                                          int m0, int n0, f32x4 (&acc)[4][4]) {
  __shared__ __align__(16) bf16_t sA[128 * 64];
  __shared__ __align__(16) bf16_t sB[128 * 64];
  const int tid = threadIdx.x;
  const int lane = tid & 63, w = tid >> 6;
  const int wr = w >> 1, wc = w & 1;
  const int quad = lane >> 4, m16 = lane & 15;
  const int srow = w * 32 + (lane >> 3);                 // + i*8
  const int gcol = (((lane & 7) ^ (lane >> 3)) * 8);     // global k-offset within tile
  const int swz7 = m16 & 7;                              // frag-read swizzle
  for (int k0 = 0; k0 < 2048; k0 += 64) {
    __syncthreads();
#pragma unroll
    for (int i = 0; i < 4; ++i) {
      gload_lds16(A + (size_t)(m0 + srow + i * 8) * 2048 + k0 + gcol,
                  sA + (size_t)(w * 32 + i * 8) * 64 + lane * 8);
      gload_lds16(W + (size_t)(n0 + srow + i * 8) * 2048 + k0 + gcol,
                  sB + (size_t)(w * 32 + i * 8) * 64 + lane * 8);
    }
    __syncthreads();
#pragma unroll
    for (int kk = 0; kk < 2; ++kk) {
      short8 af[4], bf[4];
#pragma unroll
      for (int i = 0; i < 4; ++i)
        af[i] = *(const short8*)(sA + (wr * 64 + i * 16 + m16) * 64 +
                                 ((kk * 4 + quad) ^ swz7) * 8);
#pragma unroll
      for (int j = 0; j < 4; ++j)
        bf[j] = *(const short8*)(sB + (wc * 64 + j * 16 + m16) * 64 +
                                 ((kk * 4 + quad) ^ swz7) * 8);
#pragma unroll
      for (int i = 0; i < 4; ++i)
#pragma unroll
        for (int j = 0; j < 4; ++j)
          acc[i][j] = __builtin_amdgcn_mfma_f32_16x16x32_bf16(af[i], bf[j], acc[i][j], 0, 0, 0);
    }
  }
}

// ---------------------------------------------------------------- QKV GEMM: 256x192, 4-phase
// C[m,n] = sum_k A[m,k]*W[n,k]; A: 4096x2048, W: 6144x2048. Grid (16,32) = 512 blocks =
// exactly 2 full rounds of 256 CUs (zero tail). 8 waves (2M x 4N), per-wave 128x48 =
// acc[8][3]. BK=64, double-buffered LDS (112 KiB).
// Phase ph (kk=ph>>1, mh=ph&1): ds_read af[mh*4..+3][kk] (4) + bf[0..2][kk] at mh==0 (3),
// stage, s_barrier, setprio(1), 12 MFMA, setprio(0), s_barrier. Reads/phase: 7/4/7/4.
// Stage schedule (clobber-safe): A(t+1)->buf q at ph0 (half0) / ph1 (half1) — different
// buffer than current A reads, never clashes. B(t+2)->buf p at ph3 (3 chunk loads) —
// all B-reads of tile t complete by the ph2-end barrier. Boundary wait vmcnt(3): FIFO
// outstanding = B(t+1)3 + A(t+1)4 + B(t+2)3 = 10, drain oldest 7 = B(t+1)+A(t+1),
// leave B(t+2) in flight. Drain-0 only at t==NT-2.
// cols 0..4095 -> qk (Qr|Qi|Kr|Ki, Q pre-scaled); 4096..6143 -> V transposed.
__global__ __launch_bounds__(512, 2) void gemm_qkv_k(const bf16_t* __restrict__ A,
                                                     const bf16_t* __restrict__ W,
                                                     bf16_t* __restrict__ qk,
                                                     bf16_t* __restrict__ vt) {
  __shared__ __align__(16) bf16_t sA[2][256 * 64];  // 64 KB
  __shared__ __align__(16) bf16_t sB[2][192 * 64];  // 48 KB
  const int tid = threadIdx.x, lane = tid & 63, w = tid >> 6;
  const int wm = w >> 2, wn = w & 3;
  const int quad = lane >> 4, m16 = lane & 15;
  const int swz7 = m16 & 7;
  const int m0 = blockIdx.x * 256, n0 = blockIdx.y * 192;
  const int NT = 32;

  // staging geometry: lane covers row offset lane>>3, chunk (lane&7)^(lane>>3) (row&7==lane>>3)
  const int l3 = lane >> 3;
  const int gcol = (((lane & 7) ^ l3) * 8);

  f32x4 acc[8][3] = {};

  auto stageA = [&](int buf, int half, int k0) {   // 128 rows, 2 instr/wave (16 rows each)
#pragma unroll
    for (int i = 0; i < 2; ++i)
      gload_lds16(A + (size_t)(m0 + half * 128 + w * 16 + i * 8 + l3) * 2048 + k0 + gcol,
                  &sA[buf][(size_t)(half * 128 + w * 16 + i * 8) * 64] + lane * 8);
  };
  auto stageB = [&](int buf, int c, int k0) {      // 64-row chunk c, 1 instr/wave (8 rows)
    gload_lds16(W + (size_t)(n0 + c * 64 + w * 8 + l3) * 2048 + k0 + gcol,
                &sB[buf][(size_t)(c * 64 + w * 8) * 64] + lane * 8);
  };

  // prologue: A(0) 4 loads, B(0) 3, B(1) 3 -> 10 outstanding; drain A(0)+B(0) = oldest 7.
  stageA(0, 0, 0); stageA(0, 1, 0);
  stageB(0, 0, 0); stageB(0, 1, 0); stageB(0, 2, 0);
  stageB(1, 0, 64); stageB(1, 1, 64); stageB(1, 2, 64);
  asm volatile("s_waitcnt vmcnt(3)" ::: "memory");
  __builtin_amdgcn_s_barrier();

  for (int t = 0; t < NT; ++t) {
    const int p = t & 1, q = p ^ 1;
    const bf16_t* sAp = sA[p];
    const bf16_t* sBp = sB[p];
    short8 af[4], bfr[3];
#pragma unroll
    for (int ph = 0; ph < 4; ++ph) {
      const int kk = ph >> 1, mh = ph & 1;
      // ds reads for this phase (balanced: 7/4/7/4)
#pragma unroll
      for (int i = 0; i < 4; ++i)
        af[i] = *(const short8*)(sAp + (wm * 128 + (mh * 4 + i) * 16 + m16) * 64 +
                                 ((kk * 4 + quad) ^ swz7) * 8);
      if (mh == 0) {
#pragma unroll
        for (int j = 0; j < 3; ++j)
          bfr[j] = *(const short8*)(sBp + (wn * 48 + j * 16 + m16) * 64 +
                                    ((kk * 4 + quad) ^ swz7) * 8);
      }
      // stage (guards uniform across block)
      if (ph == 0)      { if (t + 1 < NT) stageA(q, 0, (t + 1) * 64); }
      else if (ph == 1) { if (t + 1 < NT) stageA(q, 1, (t + 1) * 64); }
      else if (ph == 3) {
        if (t + 2 < NT) {
          stageB(p, 0, (t + 2) * 64); stageB(p, 1, (t + 2) * 64); stageB(p, 2, (t + 2) * 64);
        }
      }
      asm volatile("" ::: "memory");
      __builtin_amdgcn_s_barrier();
      __builtin_amdgcn_s_setprio(1);
#pragma unroll
      for (int i = 0; i < 4; ++i)
#pragma unroll
        for (int j = 0; j < 3; ++j)
          acc[mh * 4 + i][j] = __builtin_amdgcn_mfma_f32_16x16x32_bf16(af[i], bfr[j],
                                                                       acc[mh * 4 + i][j], 0, 0, 0);
      __builtin_amdgcn_s_setprio(0);
      asm volatile("" ::: "memory");
      if (ph == 3) {
        if (t == NT - 2)      asm volatile("s_waitcnt vmcnt(0)" ::: "memory");
        else if (t < NT - 2)  asm volatile("s_waitcnt vmcnt(3)" ::: "memory");
      }
      __builtin_amdgcn_s_barrier();
    }
  }

  // epilogue
#pragma unroll
  for (int mf = 0; mf < 8; ++mf) {
    const int rowb = m0 + wm * 128 + mf * 16 + quad * 4;   // C/D row = quad*4 + reg
#pragma unroll
    for (int nf = 0; nf < 3; ++nf) {
      const int col = n0 + wn * 48 + nf * 16 + m16;        // C/D col = lane&15
      if (col < 4096) {
        const float sc = (col < 2048) ? 0.125f : 1.f;      // pre-scale Q by SCALE
#pragma unroll
        for (int r = 0; r < 4; ++r)
          qk[(size_t)(rowb + r) * 4096 + col] = __float2bfloat16(acc[mf][nf][r] * sc);
      } else {
        const int vcol = col - 4096;
        const int ri = vcol >> 10, dfeat = vcol & 1023;
        const int b = rowb >> 11, seq = rowb & 2047;
        const size_t vrow = (size_t)(b * 2048 + (dfeat >> 6) * 128 + ri * 64 + (dfeat & 63));
        unsigned int lo = (unsigned)bfbits(acc[mf][nf][0]) | ((unsigned)bfbits(acc[mf][nf][1]) << 16);
        unsigned int hi = (unsigned)bfbits(acc[mf][nf][2]) | ((unsigned)bfbits(acc[mf][nf][3]) << 16);
        *(uint2*)(vt + vrow * 2048 + seq) = make_uint2(lo, hi);
      }
    }
  }
}

// Output GEMM: N=2048 ([yr|yi]), fp32 out + bias. 128x128 core.
__global__ __launch_bounds__(256) void gemm_out_k(const bf16_t* __restrict__ A,
                                                  const bf16_t* __restrict__ W,
                                                  const float* __restrict__ bor,
                                                  const float* __restrict__ boi,
                                                  float* __restrict__ out) {
  f32x4 acc[4][4] = {};
  const int m0 = blockIdx.x * 128, n0 = blockIdx.y * 128;
  gemm_core(A, W, m0, n0, acc);
  const int lane = threadIdx.x & 63, w = threadIdx.x >> 6;
  const int wr = w >> 1, wc = w & 1, quad = lane >> 4, m16 = lane & 15;
#pragma unroll
  for (int i = 0; i < 4; ++i) {
    const int rowb = m0 + wr * 64 + i * 16 + quad * 4;
#pragma unroll
    for (int j = 0; j < 4; ++j) {
      const int col = n0 + wc * 64 + j * 16 + m16;
      float bias; float* op;
      if (col < 1024) { bias = bor[col]; op = out + col; }
      else            { bias = boi[col - 1024]; op = out + 4194304 + (col - 1024); }
#pragma unroll
      for (int r = 0; r < 4; ++r)
        op[(size_t)(rowb + r) * 1024] = acc[i][j][r] + bias;
    }
  }
}

// ---------------------------------------------------------------- flash attention
// grid (16, B*H), 512 threads = 8 waves. Waves 0-3 own 16 q-rows each of subtile
// A = x*64..; waves 4-7 own subtile B = (31-x)*64.. . Shared staged K/V tile,
// joint k-loop over nT=32-x tiles, BK=64. Fixed-max softmax, ones-row-MFMA row sums.
__global__ __launch_bounds__(512, 4) void attn_k(const bf16_t* __restrict__ qk,
                                                 const bf16_t* __restrict__ vt,
                                                 bf16_t* __restrict__ acat) {
  __shared__ __align__(16) bf16_t sK[64 * 128];       // 16 KB
  __shared__ __align__(16) bf16_t sV[144 * 64];       // 18 KB (rows 128..143: ones/zeros)
  __shared__ __align__(16) bf16_t sP[8][16 * 72];     // 18 KB (one slab per wave)
  const int tid = threadIdx.x, lane = tid & 63, w = tid >> 6;
  const int wq = w & 3, sub = w >> 2;                 // sub 0 = subtile A, 1 = subtile B
  const int quad = lane >> 4, m16 = lane & 15;
  const int x = blockIdx.x, bh = blockIdx.y, b = bh >> 4, h = bh & 15;
  const size_t qkrow0 = (size_t)b * 2048;
  const int qA = x * 64, qB = (31 - x) * 64;
  const int nT = 32 - x;
  const int swz7 = m16 & 7;
  const int qbase = (sub ? qB : qA) + wq * 16;

  // preset sV rows 128..143: row 128 = ones, rest zeros (constant rows: swizzle-invariant)
  if (tid < 256) {
    const int rr = tid >> 4, cb = (tid & 15) * 4;
    const bf16_t v = __float2bfloat16(rr == 0 ? 1.f : 0.f);
#pragma unroll
    for (int i = 0; i < 4; ++i) sV[(128 + rr) * 64 + cb + i] = v;
  }

  // Q fragments for this wave's 16 rows (A-operand: m=lane&15, k=quad*8+j), d-chunks of 32
  short8 qf[4];
  {
    const bf16_t* qa = qk + (qkrow0 + qbase + m16) * 4096;
#pragma unroll
    for (int kk = 0; kk < 4; ++kk) {
      const int col = (kk >> 1) * 1024 + h * 64 + (kk & 1) * 32 + quad * 8;
      qf[kk] = *(const short8*)(qa + col);
    }
  }
  f32x4 o[9];
#pragma unroll
  for (int j = 0; j < 9; ++j) o[j] = (f32x4){0.f, 0.f, 0.f, 0.f};

  const int qrow = qbase + quad * 4;

  // staging geometry
  const int kl4 = lane >> 4, kl15 = lane & 15;   // K tile: 4 rows/instr (256 B rows)
  const int vl3 = lane >> 3;                     // V tile: 8 rows/instr (128 B rows)
  const int vg7 = ((lane & 7) ^ vl3) * 8;

  for (int t = 0; t < nT; ++t) {
    const int k0 = t * 64;
    __syncthreads();
    // stage K: 64 rows x 128 elem (Kr|Ki of head h); wave w covers rows w*8+i*4+kl4
#pragma unroll
    for (int i = 0; i < 2; ++i) {
      const int row = w * 8 + i * 4 + kl4;
      const int g = kl15 ^ (row & 7);            // low-3 XOR; bit3 of kl15 preserved
      const int col = 2048 + (g >> 3) * 1024 + h * 64 + (g & 7) * 8;
      gload_lds16(qk + (qkrow0 + k0 + row) * 4096 + col,
                  sK + (size_t)(w * 8 + i * 4) * 128 + lane * 8);
    }
    // stage V^T: 128 d-rows x 64 k; wave w covers rows w*16+i*8+vl3
#pragma unroll
    for (int i = 0; i < 2; ++i) {
      const int row = w * 16 + i * 8 + vl3;
      gload_lds16(vt + ((size_t)bh * 128 + row) * 2048 + k0 + vg7,
                  sV + (size_t)(w * 16 + i * 8) * 64 + lane * 8);
    }
    __syncthreads();

    const bool act = sub ? true : (t <= x);      // B-waves always active
    if (act) {
      const bool dg = sub ? (t == nT - 1) : (t == x);

      // ---- S = Qs·K^T (16 q-rows x 64 k)
      f32x4 sv[4];
#pragma unroll
      for (int jt = 0; jt < 4; ++jt) {
        f32x4 a = (f32x4){0.f, 0.f, 0.f, 0.f};
#pragma unroll
        for (int kk = 0; kk < 4; ++kk) {
          short8 kf = *(const short8*)(sK + (jt * 16 + m16) * 128 +
                                       ((kk * 4 + quad) ^ swz7) * 8);
          a = __builtin_amdgcn_mfma_f32_16x16x32_bf16(qf[kk], kf, a, 0, 0, 0);
        }
        sv[jt] = a;
      }

      // ---- fixed-max softmax: P = exp(S), C-layout -> A-layout via per-wave sP
      bf16_t* pw = sP[w];
#pragma unroll
      for (int jt = 0; jt < 4; ++jt)
#pragma unroll
        for (int r = 0; r < 4; ++r) {
          float s = sv[jt][r];
          if (dg && (k0 + jt * 16 + m16 > qrow + r)) s = -1e30f;
          pw[(quad * 4 + r) * 72 + jt * 16 + m16] = __float2bfloat16(__expf(s));
        }
      asm volatile("s_waitcnt lgkmcnt(0)" ::: "memory");  // own-wave P write->read

      // ---- O += P·V (j=8 = ones-row -> row sums l)
#pragma unroll
      for (int kc = 0; kc < 2; ++kc) {
        short8 p = *(const short8*)(pw + m16 * 72 + kc * 32 + quad * 8);
#pragma unroll
        for (int j = 0; j < 9; ++j) {
          short8 vf = *(const short8*)(sV + (j * 16 + m16) * 64 +
                                       ((kc * 4 + quad) ^ swz7) * 8);
          o[j] = __builtin_amdgcn_mfma_f32_16x16x32_bf16(p, vf, o[j], 0, 0, 0);
        }
      }
    }
  }

  // ---- epilogue: l broadcast from lane (quad*16), normalize, write [B,L,2048]=[out_r|out_i]
  float inv[4];
#pragma unroll
  for (int r = 0; r < 4; ++r)
    inv[r] = 1.f / __shfl(o[8][r], lane & 48);
#pragma unroll
  for (int j = 0; j < 8; ++j) {
    const int d = j * 16 + m16;
    const int col = (d < 64) ? (h * 64 + d) : (1024 + h * 64 + (d - 64));
#pragma unroll
    for (int r = 0; r < 4; ++r)
      acat[((size_t)b * 2048 + qrow + r) * 2048 + col] = __float2bfloat16(o[j][r] * inv[r]);
  }
}

// ---------------------------------------------------------------- launch
extern "C" void kernel_launch(void* const* d_in, const int* in_sizes, int n_in,
                              void* d_out, int out_size, void* d_ws, size_t ws_size,
                              hipStream_t stream) {
  const float* xr  = (const float*)d_in[0];
  const float* xi  = (const float*)d_in[1];
  const float* wqr = (const float*)d_in[2];
  const float* wqi = (const float*)d_in[3];
  const float* wkr = (const float*)d_in[4];
  const float* wki = (const float*)d_in[5];
  const float* wvr = (const float*)d_in[6];
  const float* wvi = (const float*)d_in[7];
  const float* wor = (const float*)d_in[8];
  const float* woi = (const float*)d_in[9];
  const float* bor = (const float*)d_in[10];
  const float* boi = (const float*)d_in[11];
  float* out = (float*)d_out;

  char* ws = (char*)d_ws;
  bf16_t* Xcat = (bf16_t*)(ws);                   // 4096x2048   16 MB
  bf16_t* Wqkv = (bf16_t*)(ws + 16777216ull);     // 6144x2048   24 MB
  bf16_t* QKb  = (bf16_t*)(ws + 41943040ull);     // 4096x4096   32 MB
  bf16_t* Vt   = (bf16_t*)(ws + 75497472ull);     // 4096x2048   16 MB (V transposed)
  bf16_t* Acat = (bf16_t*)(ws + 92274688ull);     // 4096x2048   16 MB
  bf16_t* Wo   = (bf16_t*)(ws + 109051904ull);    // 2048x2048    8 MB

  pack_x_k<<<2048, 256, 0, stream>>>(xr, xi, Xcat);
  pack_wqkv_k<<<2048, 256, 0, stream>>>(wqr, wqi, wkr, wki, wvr, wvi, Wqkv);
  pack_wo_k<<<1024, 256, 0, stream>>>(wor, woi, Wo);
  gemm_qkv_k<<<dim3(16, 32), 512, 0, stream>>>(Xcat, Wqkv, QKb, Vt);
  attn_k<<<dim3(16, 32), 512, 0, stream>>>(QKb, Vt, Acat);
  gemm_out_k<<<dim3(32, 16), 256, 0, stream>>>(Acat, Wo, bor, boi, out);
}

// Round 4
// 352.252 us; speedup vs baseline: 1.0885x; 1.0128x over previous
//
#include <hip/hip_runtime.h>
#include <hip/hip_bf16.h>

// ComplexAttention: B=2, L=2048, D=1024, H=16, HD=64, SCALE=0.125
// Pipeline: pack(x,w) -> bf16 GEMM (QKV: 256x192 tile, software-pipelined phases,
//           1 barrier/K-tile, counted vmcnt; Q pre-scaled, V stored transposed)
//           -> flash attn (8-wave paired q-tiles) -> bf16 GEMM 128x128.
// All LDS tiles staged via global_load_lds(16B) with XOR-16B-chunk swizzle
// (chunk' = chunk ^ (row&7)) folded into the GLOBAL address so LDS stays
// contiguous (wave-uniform base + lane*16 contract) yet frag reads are ~conflict-free.

using f32x4  = __attribute__((ext_vector_type(4))) float;
using short8 = __attribute__((ext_vector_type(8))) short;   // 8 bf16 = 4 VGPRs (MFMA A/B frag)
using bf16_t = __hip_bfloat16;

#define AS1 __attribute__((address_space(1)))
#define AS3 __attribute__((address_space(3)))

__device__ __forceinline__ void gload_lds16(const bf16_t* g, bf16_t* l) {
  __builtin_amdgcn_global_load_lds((const AS1 unsigned int*)g, (AS3 unsigned int*)l, 16, 0, 0);
}

__device__ __forceinline__ unsigned short bfbits(float f) {
  union { bf16_t h; unsigned short u; } c; c.h = __float2bfloat16(f); return c.u;
}

// ---------------------------------------------------------------- pack kernels
__global__ void pack_x_k(const float* __restrict__ xr, const float* __restrict__ xi,
                         bf16_t* __restrict__ out) {
  const int total4 = 4096 * 2048 / 4;
  for (int idx = blockIdx.x * blockDim.x + threadIdx.x; idx < total4;
       idx += gridDim.x * blockDim.x) {
    int m = idx >> 9, k = (idx & 511) * 4;
    const float* src = (k < 1024) ? (xr + (size_t)m * 1024 + k)
                                  : (xi + (size_t)m * 1024 + (k - 1024));
    float4 v = *(const float4*)src;
    unsigned int lo = (unsigned)bfbits(v.x) | ((unsigned)bfbits(v.y) << 16);
    unsigned int hi = (unsigned)bfbits(v.z) | ((unsigned)bfbits(v.w) << 16);
    *(uint2*)(out + (size_t)idx * 4) = make_uint2(lo, hi);
  }
}

__global__ void pack_wqkv_k(const float* __restrict__ wqr, const float* __restrict__ wqi,
                            const float* __restrict__ wkr, const float* __restrict__ wki,
                            const float* __restrict__ wvr, const float* __restrict__ wvi,
                            bf16_t* __restrict__ out) {
  const int total4 = 6144 * 2048 / 4;
  for (int idx = blockIdx.x * blockDim.x + threadIdx.x; idx < total4;
       idx += gridDim.x * blockDim.x) {
    int row = idx >> 9, k = (idx & 511) * 4;
    int sec = row >> 10, r1 = row & 1023;
    bool lowk = (k < 1024);
    int kk = lowk ? k : (k - 1024);
    const float* base = wqr; float sg = 1.f;
    switch (sec) {
      case 0: base = lowk ? wqr : wqi; sg = lowk ? 1.f : -1.f; break;
      case 1: base = lowk ? wqi : wqr; break;
      case 2: base = lowk ? wkr : wki; sg = lowk ? 1.f : -1.f; break;
      case 3: base = lowk ? wki : wkr; break;
      case 4: base = lowk ? wvr : wvi; sg = lowk ? 1.f : -1.f; break;
      case 5: base = lowk ? wvi : wvr; break;
    }
    float4 v = *(const float4*)(base + (size_t)r1 * 1024 + kk);
    unsigned int lo = (unsigned)bfbits(v.x * sg) | ((unsigned)bfbits(v.y * sg) << 16);
    unsigned int hi = (unsigned)bfbits(v.z * sg) | ((unsigned)bfbits(v.w * sg) << 16);
    *(uint2*)(out + (size_t)idx * 4) = make_uint2(lo, hi);
  }
}

__global__ void pack_wo_k(const float* __restrict__ wor, const float* __restrict__ woi,
                          bf16_t* __restrict__ out) {
  const int total4 = 2048 * 2048 / 4;
  for (int idx = blockIdx.x * blockDim.x + threadIdx.x; idx < total4;
       idx += gridDim.x * blockDim.x) {
    int row = idx >> 9, k = (idx & 511) * 4;
    int sec = row >> 10, r1 = row & 1023;
    bool lowk = (k < 1024);
    int kk = lowk ? k : (k - 1024);
    const float* base; float sg = 1.f;
    if (sec == 0) { base = lowk ? wor : woi; sg = lowk ? 1.f : -1.f; }
    else          { base = lowk ? woi : wor; }
    float4 v = *(const float4*)(base + (size_t)r1 * 1024 + kk);
    unsigned int lo = (unsigned)bfbits(v.x * sg) | ((unsigned)bfbits(v.y * sg) << 16);
    unsigned int hi = (unsigned)bfbits(v.z * sg) | ((unsigned)bfbits(v.w * sg) << 16);
    *(uint2*)(out + (size_t)idx * 4) = make_uint2(lo, hi);
  }
}

// ---------------------------------------------------------------- GEMM core 128x128 (gemm_out)
__device__ __forceinline__ void gemm_core(const bf16_t* __restrict__ A,
                                          const bf16_t* __restrict__ W,
                                          int m0, int n0, f32x4 (&acc)[4][4]) {
  __shared__ __align__(16) bf16_t sA[128 * 64];
  __shared__ __align__(16) bf16_t sB[128 * 64];
  const int tid = threadIdx.x;
  const int lane = tid & 63, w = tid >> 6;
  const int wr = w >> 1, wc = w & 1;
  const int quad = lane >> 4, m16 = lane & 15;
  const int srow = w * 32 + (lane >> 3);                 // + i*8
  const int gcol = (((lane & 7) ^ (lane >> 3)) * 8);     // global k-offset within tile
  const int swz7 = m16 & 7;                              // frag-read swizzle
  for (int k0 = 0; k0 < 2048; k0 += 64) {
    __syncthreads();
#pragma unroll
    for (int i = 0; i < 4; ++i) {
      gload_lds16(A + (size_t)(m0 + srow + i * 8) * 2048 + k0 + gcol,
                  sA + (size_t)(w * 32 + i * 8) * 64 + lane * 8);
      gload_lds16(W + (size_t)(n0 + srow + i * 8) * 2048 + k0 + gcol,
                  sB + (size_t)(w * 32 + i * 8) * 64 + lane * 8);
    }
    __syncthreads();
#pragma unroll
    for (int kk = 0; kk < 2; ++kk) {
      short8 af[4], bf[4];
#pragma unroll
      for (int i = 0; i < 4; ++i)
        af[i] = *(const short8*)(sA + (wr * 64 + i * 16 + m16) * 64 +
                                 ((kk * 4 + quad) ^ swz7) * 8);
#pragma unroll
      for (int j = 0; j < 4; ++j)
        bf[j] = *(const short8*)(sB + (wc * 64 + j * 16 + m16) * 64 +
                                 ((kk * 4 + quad) ^ swz7) * 8);
#pragma unroll
      for (int i = 0; i < 4; ++i)
#pragma unroll
        for (int j = 0; j < 4; ++j)
          acc[i][j] = __builtin_amdgcn_mfma_f32_16x16x32_bf16(af[i], bf[j], acc[i][j], 0, 0, 0);
    }
  }
}

// ---------------------------------------------------------------- QKV GEMM: 256x192, pipelined
// C[m,n] = sum_k A[m,k]*W[n,k]; A: 4096x2048, W: 6144x2048. Grid (16,32) = 512 blocks =
// exactly 2 rounds of 256 CUs. 8 waves (2M x 4N), per-wave 128x48 = acc[8][3]. BK=64,
// double-buffered LDS (112 KiB).
// SOFTWARE-PIPELINED phases: phase k's MFMA consumes frags read during phase k-1, and
// issues the reads for phase k+1 BEFORE its MFMA cluster -> LDS bursts overlap MFMA
// windows (compiler emits counted lgkmcnt, not 0). No LDS writes mid-tile (staging is
// async DMA), so inter-phase barriers are dropped: ONE vmcnt(0)+s_barrier per K-tile
// (at ph2-end, guarding ph3's reads of next-tile buffers q).
//   ph0: MFMA A0xB0 -> acc[0..3] (kk0) | read A1=af(mf4..7,kk0) | stage A(t+1)h0 -> q
//   ph1: MFMA A1xB0 -> acc[4..7]       | read A0=af(0..3,kk1), B1=bf(kk1) | stage A(t+1)h1
//   ph2: MFMA A0xB1 -> acc[0..3] (kk1) | read A1=af(4..7,kk1)
//        vmcnt(0) [drains B(t+1) (issued t-1 ph3) + A(t+1)] + s_barrier
//   ph3: MFMA A1xB1 -> acc[4..7]       | read A0,B0 of tile t+1 from bufs q
//                                      | stage B(t+2) -> sB[p] (3 chunks)
// Staging-vs-read hazards rely on: ds_reads issued pre-barrier complete ~120cy post-
// issue; DMA writes arrive >=~900cy after issue, which is >=1 barrier later (margin
// ~700cy). Same addresses/math as the 4-phase version — pure reorder.
// cols 0..4095 -> qk (Qr|Qi|Kr|Ki, Q pre-scaled); 4096..6143 -> V transposed.
__global__ __launch_bounds__(512, 2) void gemm_qkv_k(const bf16_t* __restrict__ A,
                                                     const bf16_t* __restrict__ W,
                                                     bf16_t* __restrict__ qk,
                                                     bf16_t* __restrict__ vt) {
  __shared__ __align__(16) bf16_t sA[2][256 * 64];  // 64 KB
  __shared__ __align__(16) bf16_t sB[2][192 * 64];  // 48 KB
  const int tid = threadIdx.x, lane = tid & 63, w = tid >> 6;
  const int wm = w >> 2, wn = w & 3;
  const int quad = lane >> 4, m16 = lane & 15;
  const int swz7 = m16 & 7;
  const int m0 = blockIdx.x * 256, n0 = blockIdx.y * 192;
  const int NT = 32;

  // staging geometry: lane covers row offset lane>>3, chunk (lane&7)^(lane>>3) (row&7==lane>>3)
  const int l3 = lane >> 3;
  const int gcol = (((lane & 7) ^ l3) * 8);

  f32x4 acc[8][3] = {};

  auto stageA = [&](int buf, int half, int k0) {   // 128 rows, 2 instr/wave (16 rows each)
#pragma unroll
    for (int i = 0; i < 2; ++i)
      gload_lds16(A + (size_t)(m0 + half * 128 + w * 16 + i * 8 + l3) * 2048 + k0 + gcol,
                  &sA[buf][(size_t)(half * 128 + w * 16 + i * 8) * 64] + lane * 8);
  };
  auto stageB = [&](int buf, int c, int k0) {      // 64-row chunk c, 1 instr/wave (8 rows)
    gload_lds16(W + (size_t)(n0 + c * 64 + w * 8 + l3) * 2048 + k0 + gcol,
                &sB[buf][(size_t)(c * 64 + w * 8) * 64] + lane * 8);
  };
  auto rdA = [&](const bf16_t* sAx, int mf, int kk) -> short8 {
    return *(const short8*)(sAx + (wm * 128 + mf * 16 + m16) * 64 +
                            ((kk * 4 + quad) ^ swz7) * 8);
  };
  auto rdB = [&](const bf16_t* sBx, int j, int kk) -> short8 {
    return *(const short8*)(sBx + (wn * 48 + j * 16 + m16) * 64 +
                            ((kk * 4 + quad) ^ swz7) * 8);
  };

  // prologue: stage tiles 0 and 1; drain tile 0 (keep tile 1's 7 in flight); preload ph0 frags.
  stageA(0, 0, 0); stageA(0, 1, 0);
  stageB(0, 0, 0); stageB(0, 1, 0); stageB(0, 2, 0);
  stageA(1, 0, 64); stageA(1, 1, 64);
  stageB(1, 0, 64); stageB(1, 1, 64); stageB(1, 2, 64);
  asm volatile("s_waitcnt vmcnt(7)" ::: "memory");
  __builtin_amdgcn_s_barrier();

  short8 A0[4], A1[4], B0[3], B1[3];
#pragma unroll
  for (int i = 0; i < 4; ++i) A0[i] = rdA(sA[0], i, 0);
#pragma unroll
  for (int j = 0; j < 3; ++j) B0[j] = rdB(sB[0], j, 0);

  for (int t = 0; t < NT; ++t) {
    const int p = t & 1, q = p ^ 1;
    const bf16_t* sAp = sA[p];
    const bf16_t* sBp = sB[p];
    const bf16_t* sAq = sA[q];
    const bf16_t* sBq = sB[q];
    const bool stg = (t + 1 < NT);

    // ---- ph0: MFMA A0xB0 (acc rows 0-3, kk0); read A1; stage A(t+1) half0
#pragma unroll
    for (int i = 0; i < 4; ++i) A1[i] = rdA(sAp, 4 + i, 0);
    if (stg) stageA(q, 0, (t + 1) * 64);
    __builtin_amdgcn_s_setprio(1);
#pragma unroll
    for (int i = 0; i < 4; ++i)
#pragma unroll
      for (int j = 0; j < 3; ++j)
        acc[i][j] = __builtin_amdgcn_mfma_f32_16x16x32_bf16(A0[i], B0[j], acc[i][j], 0, 0, 0);
    __builtin_amdgcn_s_setprio(0);

    // ---- ph1: MFMA A1xB0 (acc rows 4-7); read A0(kk1), B1(kk1); stage A(t+1) half1
#pragma unroll
    for (int i = 0; i < 4; ++i) A0[i] = rdA(sAp, i, 1);
#pragma unroll
    for (int j = 0; j < 3; ++j) B1[j] = rdB(sBp, j, 1);
    if (stg) stageA(q, 1, (t + 1) * 64);
    __builtin_amdgcn_s_setprio(1);
#pragma unroll
    for (int i = 0; i < 4; ++i)
#pragma unroll
      for (int j = 0; j < 3; ++j)
        acc[4 + i][j] = __builtin_amdgcn_mfma_f32_16x16x32_bf16(A1[i], B0[j], acc[4 + i][j], 0, 0, 0);
    __builtin_amdgcn_s_setprio(0);

    // ---- ph2: MFMA A0xB1 (acc rows 0-3, kk1); read A1(kk1)
#pragma unroll
    for (int i = 0; i < 4; ++i) A1[i] = rdA(sAp, 4 + i, 1);
    __builtin_amdgcn_s_setprio(1);
#pragma unroll
    for (int i = 0; i < 4; ++i)
#pragma unroll
      for (int j = 0; j < 3; ++j)
        acc[i][j] = __builtin_amdgcn_mfma_f32_16x16x32_bf16(A0[i], B1[j], acc[i][j], 0, 0, 0);
    __builtin_amdgcn_s_setprio(0);

    // ---- tile boundary sync: all waves' A(t+1)+B(t+1) staging retired before q-reads
    asm volatile("s_waitcnt vmcnt(0)" ::: "memory");
    __builtin_amdgcn_s_barrier();

    // ---- ph3: MFMA A1xB1 (acc rows 4-7); read A0,B0 of t+1 from q; stage B(t+2)->sB[p]
    if (stg) {
#pragma unroll
      for (int i = 0; i < 4; ++i) A0[i] = rdA(sAq, i, 0);
#pragma unroll
      for (int j = 0; j < 3; ++j) B0[j] = rdB(sBq, j, 0);
    }
    if (t + 2 < NT) {
      stageB(p, 0, (t + 2) * 64); stageB(p, 1, (t + 2) * 64); stageB(p, 2, (t + 2) * 64);
    }
    __builtin_amdgcn_s_setprio(1);
#pragma unroll
    for (int i = 0; i < 4; ++i)
#pragma unroll
      for (int j = 0; j < 3; ++j)
        acc[4 + i][j] = __builtin_amdgcn_mfma_f32_16x16x32_bf16(A1[i], B1[j], acc[4 + i][j], 0, 0, 0);
    __builtin_amdgcn_s_setprio(0);
  }

  // epilogue
#pragma unroll
  for (int mf = 0; mf < 8; ++mf) {
    const int rowb = m0 + wm * 128 + mf * 16 + quad * 4;   // C/D row = quad*4 + reg
#pragma unroll
    for (int nf = 0; nf < 3; ++nf) {
      const int col = n0 + wn * 48 + nf * 16 + m16;        // C/D col = lane&15
      if (col < 4096) {
        const float sc = (col < 2048) ? 0.125f : 1.f;      // pre-scale Q by SCALE
#pragma unroll
        for (int r = 0; r < 4; ++r)
          qk[(size_t)(rowb + r) * 4096 + col] = __float2bfloat16(acc[mf][nf][r] * sc);
      } else {
        const int vcol = col - 4096;
        const int ri = vcol >> 10, dfeat = vcol & 1023;
        const int b = rowb >> 11, seq = rowb & 2047;
        const size_t vrow = (size_t)(b * 2048 + (dfeat >> 6) * 128 + ri * 64 + (dfeat & 63));
        unsigned int lo = (unsigned)bfbits(acc[mf][nf][0]) | ((unsigned)bfbits(acc[mf][nf][1]) << 16);
        unsigned int hi = (unsigned)bfbits(acc[mf][nf][2]) | ((unsigned)bfbits(acc[mf][nf][3]) << 16);
        *(uint2*)(vt + vrow * 2048 + seq) = make_uint2(lo, hi);
      }
    }
  }
}

// Output GEMM: N=2048 ([yr|yi]), fp32 out + bias. 128x128 core.
__global__ __launch_bounds__(256) void gemm_out_k(const bf16_t* __restrict__ A,
                                                  const bf16_t* __restrict__ W,
                                                  const float* __restrict__ bor,
                                                  const float* __restrict__ boi,
                                                  float* __restrict__ out) {
  f32x4 acc[4][4] = {};
  const int m0 = blockIdx.x * 128, n0 = blockIdx.y * 128;
  gemm_core(A, W, m0, n0, acc);
  const int lane = threadIdx.x & 63, w = threadIdx.x >> 6;
  const int wr = w >> 1, wc = w & 1, quad = lane >> 4, m16 = lane & 15;
#pragma unroll
  for (int i = 0; i < 4; ++i) {
    const int rowb = m0 + wr * 64 + i * 16 + quad * 4;
#pragma unroll
    for (int j = 0; j < 4; ++j) {
      const int col = n0 + wc * 64 + j * 16 + m16;
      float bias; float* op;
      if (col < 1024) { bias = bor[col]; op = out + col; }
      else            { bias = boi[col - 1024]; op = out + 4194304 + (col - 1024); }
#pragma unroll
      for (int r = 0; r < 4; ++r)
        op[(size_t)(rowb + r) * 1024] = acc[i][j][r] + bias;
    }
  }
}

// ---------------------------------------------------------------- flash attention
// grid (16, B*H), 512 threads = 8 waves. Waves 0-3 own 16 q-rows each of subtile
// A = x*64..; waves 4-7 own subtile B = (31-x)*64.. . Shared staged K/V tile,
// joint k-loop over nT=32-x tiles, BK=64. Fixed-max softmax, ones-row-MFMA row sums.
__global__ __launch_bounds__(512, 4) void attn_k(const bf16_t* __restrict__ qk,
                                                 const bf16_t* __restrict__ vt,
                                                 bf16_t* __restrict__ acat) {
  __shared__ __align__(16) bf16_t sK[64 * 128];       // 16 KB
  __shared__ __align__(16) bf16_t sV[144 * 64];       // 18 KB (rows 128..143: ones/zeros)
  __shared__ __align__(16) bf16_t sP[8][16 * 72];     // 18 KB (one slab per wave)
  const int tid = threadIdx.x, lane = tid & 63, w = tid >> 6;
  const int wq = w & 3, sub = w >> 2;                 // sub 0 = subtile A, 1 = subtile B
  const int quad = lane >> 4, m16 = lane & 15;
  const int x = blockIdx.x, bh = blockIdx.y, b = bh >> 4, h = bh & 15;
  const size_t qkrow0 = (size_t)b * 2048;
  const int qA = x * 64, qB = (31 - x) * 64;
  const int nT = 32 - x;
  const int swz7 = m16 & 7;
  const int qbase = (sub ? qB : qA) + wq * 16;

  // preset sV rows 128..143: row 128 = ones, rest zeros (constant rows: swizzle-invariant)
  if (tid < 256) {
    const int rr = tid >> 4, cb = (tid & 15) * 4;
    const bf16_t v = __float2bfloat16(rr == 0 ? 1.f : 0.f);
#pragma unroll
    for (int i = 0; i < 4; ++i) sV[(128 + rr) * 64 + cb + i] = v;
  }

  // Q fragments for this wave's 16 rows (A-operand: m=lane&15, k=quad*8+j), d-chunks of 32
  short8 qf[4];
  {
    const bf16_t* qa = qk + (qkrow0 + qbase + m16) * 4096;
#pragma unroll
    for (int kk = 0; kk < 4; ++kk) {
      const int col = (kk >> 1) * 1024 + h * 64 + (kk & 1) * 32 + quad * 8;
      qf[kk] = *(const short8*)(qa + col);
    }
  }
  f32x4 o[9];
#pragma unroll
  for (int j = 0; j < 9; ++j) o[j] = (f32x4){0.f, 0.f, 0.f, 0.f};

  const int qrow = qbase + quad * 4;

  // staging geometry
  const int kl4 = lane >> 4, kl15 = lane & 15;   // K tile: 4 rows/instr (256 B rows)
  const int vl3 = lane >> 3;                     // V tile: 8 rows/instr (128 B rows)
  const int vg7 = ((lane & 7) ^ vl3) * 8;

  for (int t = 0; t < nT; ++t) {
    const int k0 = t * 64;
    __syncthreads();
    // stage K: 64 rows x 128 elem (Kr|Ki of head h); wave w covers rows w*8+i*4+kl4
#pragma unroll
    for (int i = 0; i < 2; ++i) {
      const int row = w * 8 + i * 4 + kl4;
      const int g = kl15 ^ (row & 7);            // low-3 XOR; bit3 of kl15 preserved
      const int col = 2048 + (g >> 3) * 1024 + h * 64 + (g & 7) * 8;
      gload_lds16(qk + (qkrow0 + k0 + row) * 4096 + col,
                  sK + (size_t)(w * 8 + i * 4) * 128 + lane * 8);
    }
    // stage V^T: 128 d-rows x 64 k; wave w covers rows w*16+i*8+vl3
#pragma unroll
    for (int i = 0; i < 2; ++i) {
      const int row = w * 16 + i * 8 + vl3;
      gload_lds16(vt + ((size_t)bh * 128 + row) * 2048 + k0 + vg7,
                  sV + (size_t)(w * 16 + i * 8) * 64 + lane * 8);
    }
    __syncthreads();

    const bool act = sub ? true : (t <= x);      // B-waves always active
    if (act) {
      const bool dg = sub ? (t == nT - 1) : (t == x);

      // ---- S = Qs·K^T (16 q-rows x 64 k)
      f32x4 sv[4];
#pragma unroll
      for (int jt = 0; jt < 4; ++jt) {
        f32x4 a = (f32x4){0.f, 0.f, 0.f, 0.f};
#pragma unroll
        for (int kk = 0; kk < 4; ++kk) {
          short8 kf = *(const short8*)(sK + (jt * 16 + m16) * 128 +
                                       ((kk * 4 + quad) ^ swz7) * 8);
          a = __builtin_amdgcn_mfma_f32_16x16x32_bf16(qf[kk], kf, a, 0, 0, 0);
        }
        sv[jt] = a;
      }

      // ---- fixed-max softmax: P = exp(S), C-layout -> A-layout via per-wave sP
      bf16_t* pw = sP[w];
#pragma unroll
      for (int jt = 0; jt < 4; ++jt)
#pragma unroll
        for (int r = 0; r < 4; ++r) {
          float s = sv[jt][r];
          if (dg && (k0 + jt * 16 + m16 > qrow + r)) s = -1e30f;
          pw[(quad * 4 + r) * 72 + jt * 16 + m16] = __float2bfloat16(__expf(s));
        }
      asm volatile("s_waitcnt lgkmcnt(0)" ::: "memory");  // own-wave P write->read

      // ---- O += P·V (j=8 = ones-row -> row sums l)
#pragma unroll
      for (int kc = 0; kc < 2; ++kc) {
        short8 p = *(const short8*)(pw + m16 * 72 + kc * 32 + quad * 8);
#pragma unroll
        for (int j = 0; j < 9; ++j) {
          short8 vf = *(const short8*)(sV + (j * 16 + m16) * 64 +
                                       ((kc * 4 + quad) ^ swz7) * 8);
          o[j] = __builtin_amdgcn_mfma_f32_16x16x32_bf16(p, vf, o[j], 0, 0, 0);
        }
      }
    }
  }

  // ---- epilogue: l broadcast from lane (quad*16), normalize, write [B,L,2048]=[out_r|out_i]
  float inv[4];
#pragma unroll
  for (int r = 0; r < 4; ++r)
    inv[r] = 1.f / __shfl(o[8][r], lane & 48);
#pragma unroll
  for (int j = 0; j < 8; ++j) {
    const int d = j * 16 + m16;
    const int col = (d < 64) ? (h * 64 + d) : (1024 + h * 64 + (d - 64));
#pragma unroll
    for (int r = 0; r < 4; ++r)
      acat[((size_t)b * 2048 + qrow + r) * 2048 + col] = __float2bfloat16(o[j][r] * inv[r]);
  }
}

// ---------------------------------------------------------------- launch
extern "C" void kernel_launch(void* const* d_in, const int* in_sizes, int n_in,
                              void* d_out, int out_size, void* d_ws, size_t ws_size,
                              hipStream_t stream) {
  const float* xr  = (const float*)d_in[0];
  const float* xi  = (const float*)d_in[1];
  const float* wqr = (const float*)d_in[2];
  const float* wqi = (const float*)d_in[3];
  const float* wkr = (const float*)d_in[4];
  const float* wki = (const float*)d_in[5];
  const float* wvr = (const float*)d_in[6];
  const float* wvi = (const float*)d_in[7];
  const float* wor = (const float*)d_in[8];
  const float* woi = (const float*)d_in[9];
  const float* bor = (const float*)d_in[10];
  const float* boi = (const float*)d_in[11];
  float* out = (float*)d_out;

  char* ws = (char*)d_ws;
  bf16_t* Xcat = (bf16_t*)(ws);                   // 4096x2048   16 MB
  bf16_t* Wqkv = (bf16_t*)(ws + 16777216ull);     // 6144x2048   24 MB
  bf16_t* QKb  = (bf16_t*)(ws + 41943040ull);     // 4096x4096   32 MB
  bf16_t* Vt   = (bf16_t*)(ws + 75497472ull);     // 4096x2048   16 MB (V transposed)
  bf16_t* Acat = (bf16_t*)(ws + 92274688ull);     // 4096x2048   16 MB
  bf16_t* Wo   = (bf16_t*)(ws + 109051904ull);    // 2048x2048    8 MB

  pack_x_k<<<2048, 256, 0, stream>>>(xr, xi, Xcat);
  pack_wqkv_k<<<2048, 256, 0, stream>>>(wqr, wqi, wkr, wki, wvr, wvi, Wqkv);
  pack_wo_k<<<1024, 256, 0, stream>>>(wor, woi, Wo);
  gemm_qkv_k<<<dim3(16, 32), 512, 0, stream>>>(Xcat, Wqkv, QKb, Vt);
  attn_k<<<dim3(16, 32), 512, 0, stream>>>(QKb, Vt, Acat);
  gemm_out_k<<<dim3(32, 16), 256, 0, stream>>>(Acat, Wo, bor, boi, out);
}

// Round 6
// 338.758 us; speedup vs baseline: 1.1319x; 1.0398x over previous
//
#include <hip/hip_runtime.h>
#include <hip/hip_bf16.h>

// ComplexAttention: B=2, L=2048, D=1024, H=16, HD=64, SCALE=0.125
// Pipeline: pack(x,w) -> bf16 GEMM (QKV: 256x192 pipelined, 2-ahead POST-BARRIER staging)
//           -> flash attn (8-wave paired q-tiles, balanced block pairing)
//           -> bf16 GEMM (out: 128x256 pipelined, 1-round grid).
// All LDS tiles staged via global_load_lds(16B) with XOR-16B-chunk swizzle
// (chunk' = chunk ^ (row&7)) folded into the GLOBAL address so LDS stays
// contiguous (wave-uniform base + lane*16 contract) yet frag reads are ~conflict-free.
// RACE DISCIPLINE (r5 lesson): DMA into a double-buffer slot is issued ONLY after the
// barrier that retires it — never pre-barrier (lagging waves may still read it).

using f32x4  = __attribute__((ext_vector_type(4))) float;
using short8 = __attribute__((ext_vector_type(8))) short;   // 8 bf16 = 4 VGPRs (MFMA A/B frag)
using bf16_t = __hip_bfloat16;

#define AS1 __attribute__((address_space(1)))
#define AS3 __attribute__((address_space(3)))

__device__ __forceinline__ void gload_lds16(const bf16_t* g, bf16_t* l) {
  __builtin_amdgcn_global_load_lds((const AS1 unsigned int*)g, (AS3 unsigned int*)l, 16, 0, 0);
}

__device__ __forceinline__ unsigned short bfbits(float f) {
  union { bf16_t h; unsigned short u; } c; c.h = __float2bfloat16(f); return c.u;
}

// ---------------------------------------------------------------- pack kernels
__global__ void pack_x_k(const float* __restrict__ xr, const float* __restrict__ xi,
                         bf16_t* __restrict__ out) {
  const int total4 = 4096 * 2048 / 4;
  for (int idx = blockIdx.x * blockDim.x + threadIdx.x; idx < total4;
       idx += gridDim.x * blockDim.x) {
    int m = idx >> 9, k = (idx & 511) * 4;
    const float* src = (k < 1024) ? (xr + (size_t)m * 1024 + k)
                                  : (xi + (size_t)m * 1024 + (k - 1024));
    float4 v = *(const float4*)src;
    unsigned int lo = (unsigned)bfbits(v.x) | ((unsigned)bfbits(v.y) << 16);
    unsigned int hi = (unsigned)bfbits(v.z) | ((unsigned)bfbits(v.w) << 16);
    *(uint2*)(out + (size_t)idx * 4) = make_uint2(lo, hi);
  }
}

__global__ void pack_wqkv_k(const float* __restrict__ wqr, const float* __restrict__ wqi,
                            const float* __restrict__ wkr, const float* __restrict__ wki,
                            const float* __restrict__ wvr, const float* __restrict__ wvi,
                            bf16_t* __restrict__ out) {
  const int total4 = 6144 * 2048 / 4;
  for (int idx = blockIdx.x * blockDim.x + threadIdx.x; idx < total4;
       idx += gridDim.x * blockDim.x) {
    int row = idx >> 9, k = (idx & 511) * 4;
    int sec = row >> 10, r1 = row & 1023;
    bool lowk = (k < 1024);
    int kk = lowk ? k : (k - 1024);
    const float* base = wqr; float sg = 1.f;
    switch (sec) {
      case 0: base = lowk ? wqr : wqi; sg = lowk ? 1.f : -1.f; break;
      case 1: base = lowk ? wqi : wqr; break;
      case 2: base = lowk ? wkr : wki; sg = lowk ? 1.f : -1.f; break;
      case 3: base = lowk ? wki : wkr; break;
      case 4: base = lowk ? wvr : wvi; sg = lowk ? 1.f : -1.f; break;
      case 5: base = lowk ? wvi : wvr; break;
    }
    float4 v = *(const float4*)(base + (size_t)r1 * 1024 + kk);
    unsigned int lo = (unsigned)bfbits(v.x * sg) | ((unsigned)bfbits(v.y * sg) << 16);
    unsigned int hi = (unsigned)bfbits(v.z * sg) | ((unsigned)bfbits(v.w * sg) << 16);
    *(uint2*)(out + (size_t)idx * 4) = make_uint2(lo, hi);
  }
}

__global__ void pack_wo_k(const float* __restrict__ wor, const float* __restrict__ woi,
                          bf16_t* __restrict__ out) {
  const int total4 = 2048 * 2048 / 4;
  for (int idx = blockIdx.x * blockDim.x + threadIdx.x; idx < total4;
       idx += gridDim.x * blockDim.x) {
    int row = idx >> 9, k = (idx & 511) * 4;
    int sec = row >> 10, r1 = row & 1023;
    bool lowk = (k < 1024);
    int kk = lowk ? k : (k - 1024);
    const float* base; float sg = 1.f;
    if (sec == 0) { base = lowk ? wor : woi; sg = lowk ? 1.f : -1.f; }
    else          { base = lowk ? woi : wor; }
    float4 v = *(const float4*)(base + (size_t)r1 * 1024 + kk);
    unsigned int lo = (unsigned)bfbits(v.x * sg) | ((unsigned)bfbits(v.y * sg) << 16);
    unsigned int hi = (unsigned)bfbits(v.z * sg) | ((unsigned)bfbits(v.w * sg) << 16);
    *(uint2*)(out + (size_t)idx * 4) = make_uint2(lo, hi);
  }
}

// ---------------------------------------------------------------- QKV GEMM: 256x192, pipelined
// Grid (16,32) = 512 blocks = 2 rounds. 8 waves (2M x 4N), per-wave 128x48 = acc[8][3].
// BK=64, dbuf LDS 112 KiB. Phases pipelined (frag reads one phase ahead of their MFMA):
//   ph0: read A1(kk0)                  | MFMA A0xB0 -> acc[0..3]
//   ph1: read A0(kk1), B1(kk1)         | MFMA A1xB0 -> acc[4..7]
//   ph2: read A1(kk1)                  | MFMA A0xB1 -> acc[0..3]
//   boundary: vmcnt(0) + s_barrier     (drains EXACTLY tile t+1's 7 loads, issued ph3
//                                       of t-1, ~4 phases earlier -> HBM latency covered)
//   ph3: read A0,B0 of t+1 from bufs q | stage ALL of tile t+2 -> bufs p (post-barrier:
//        p is dead, every wave's last p-read was ph2) | MFMA A1xB1 -> acc[4..7]
// cols 0..4095 -> qk (Qr|Qi|Kr|Ki, Q pre-scaled); 4096..6143 -> V transposed.
__global__ __launch_bounds__(512, 2) void gemm_qkv_k(const bf16_t* __restrict__ A,
                                                     const bf16_t* __restrict__ W,
                                                     bf16_t* __restrict__ qk,
                                                     bf16_t* __restrict__ vt) {
  __shared__ __align__(16) bf16_t sA[2][256 * 64];  // 64 KB
  __shared__ __align__(16) bf16_t sB[2][192 * 64];  // 48 KB
  const int tid = threadIdx.x, lane = tid & 63, w = tid >> 6;
  const int wm = w >> 2, wn = w & 3;
  const int quad = lane >> 4, m16 = lane & 15;
  const int swz7 = m16 & 7;
  const int m0 = blockIdx.x * 256, n0 = blockIdx.y * 192;
  const int NT = 32;

  const int l3 = lane >> 3;
  const int gcol = (((lane & 7) ^ l3) * 8);

  f32x4 acc[8][3] = {};

  auto stageA = [&](int buf, int half, int k0) {   // one 128-row half, 2 instr/wave
#pragma unroll
    for (int i = 0; i < 2; ++i)
      gload_lds16(A + (size_t)(m0 + half * 128 + w * 16 + i * 8 + l3) * 2048 + k0 + gcol,
                  &sA[buf][(size_t)(half * 128 + w * 16 + i * 8) * 64] + lane * 8);
  };
  auto stageB = [&](int buf, int c, int k0) {      // 64-row chunk c, 1 instr/wave
    gload_lds16(W + (size_t)(n0 + c * 64 + w * 8 + l3) * 2048 + k0 + gcol,
                &sB[buf][(size_t)(c * 64 + w * 8) * 64] + lane * 8);
  };
  auto rdA = [&](const bf16_t* sAx, int mf, int kk) -> short8 {
    return *(const short8*)(sAx + (wm * 128 + mf * 16 + m16) * 64 +
                            ((kk * 4 + quad) ^ swz7) * 8);
  };
  auto rdB = [&](const bf16_t* sBx, int j, int kk) -> short8 {
    return *(const short8*)(sBx + (wn * 48 + j * 16 + m16) * 64 +
                            ((kk * 4 + quad) ^ swz7) * 8);
  };

  // prologue: stage tiles 0 and 1 fully; drain tile 0 (leave tile 1's 7 in flight).
  stageA(0, 0, 0); stageA(0, 1, 0);
  stageB(0, 0, 0); stageB(0, 1, 0); stageB(0, 2, 0);
  stageA(1, 0, 64); stageA(1, 1, 64);
  stageB(1, 0, 64); stageB(1, 1, 64); stageB(1, 2, 64);
  asm volatile("s_waitcnt vmcnt(7)" ::: "memory");
  __builtin_amdgcn_s_barrier();

  short8 A0[4], A1[4], B0[3], B1[3];
#pragma unroll
  for (int i = 0; i < 4; ++i) A0[i] = rdA(sA[0], i, 0);
#pragma unroll
  for (int j = 0; j < 3; ++j) B0[j] = rdB(sB[0], j, 0);

  for (int t = 0; t < NT; ++t) {
    const int p = t & 1, q = p ^ 1;
    const bf16_t* sAp = sA[p];
    const bf16_t* sBp = sB[p];
    const bf16_t* sAq = sA[q];
    const bf16_t* sBq = sB[q];
    const bool stg = (t + 1 < NT);
    const bool stg2 = (t + 2 < NT);

    // ---- ph0: read A1(kk0); MFMA A0xB0 (acc rows 0-3)
#pragma unroll
    for (int i = 0; i < 4; ++i) A1[i] = rdA(sAp, 4 + i, 0);
    __builtin_amdgcn_s_setprio(1);
#pragma unroll
    for (int i = 0; i < 4; ++i)
#pragma unroll
      for (int j = 0; j < 3; ++j)
        acc[i][j] = __builtin_amdgcn_mfma_f32_16x16x32_bf16(A0[i], B0[j], acc[i][j], 0, 0, 0);
    __builtin_amdgcn_s_setprio(0);

    // ---- ph1: read A0(kk1), B1(kk1); MFMA A1xB0 (acc rows 4-7)
#pragma unroll
    for (int i = 0; i < 4; ++i) A0[i] = rdA(sAp, i, 1);
#pragma unroll
    for (int j = 0; j < 3; ++j) B1[j] = rdB(sBp, j, 1);
    __builtin_amdgcn_s_setprio(1);
#pragma unroll
    for (int i = 0; i < 4; ++i)
#pragma unroll
      for (int j = 0; j < 3; ++j)
        acc[4 + i][j] = __builtin_amdgcn_mfma_f32_16x16x32_bf16(A1[i], B0[j], acc[4 + i][j], 0, 0, 0);
    __builtin_amdgcn_s_setprio(0);

    // ---- ph2: read A1(kk1); MFMA A0xB1 (acc rows 0-3)
#pragma unroll
    for (int i = 0; i < 4; ++i) A1[i] = rdA(sAp, 4 + i, 1);
    __builtin_amdgcn_s_setprio(1);
#pragma unroll
    for (int i = 0; i < 4; ++i)
#pragma unroll
      for (int j = 0; j < 3; ++j)
        acc[i][j] = __builtin_amdgcn_mfma_f32_16x16x32_bf16(A0[i], B1[j], acc[i][j], 0, 0, 0);
    __builtin_amdgcn_s_setprio(0);

    // ---- tile boundary: exact drain of tile t+1's staging (issued ph3 of t-1)
    asm volatile("s_waitcnt vmcnt(0)" ::: "memory");
    __builtin_amdgcn_s_barrier();

    // ---- ph3: read A0,B0 of t+1 from q; stage ALL of tile t+2 -> p; MFMA A1xB1
    if (stg) {
#pragma unroll
      for (int i = 0; i < 4; ++i) A0[i] = rdA(sAq, i, 0);
#pragma unroll
      for (int j = 0; j < 3; ++j) B0[j] = rdB(sBq, j, 0);
    }
    if (stg2) {
      stageA(p, 0, (t + 2) * 64); stageA(p, 1, (t + 2) * 64);
      stageB(p, 0, (t + 2) * 64); stageB(p, 1, (t + 2) * 64); stageB(p, 2, (t + 2) * 64);
    }
    __builtin_amdgcn_s_setprio(1);
#pragma unroll
    for (int i = 0; i < 4; ++i)
#pragma unroll
      for (int j = 0; j < 3; ++j)
        acc[4 + i][j] = __builtin_amdgcn_mfma_f32_16x16x32_bf16(A1[i], B1[j], acc[4 + i][j], 0, 0, 0);
    __builtin_amdgcn_s_setprio(0);
  }

  // epilogue
#pragma unroll
  for (int mf = 0; mf < 8; ++mf) {
    const int rowb = m0 + wm * 128 + mf * 16 + quad * 4;   // C/D row = quad*4 + reg
#pragma unroll
    for (int nf = 0; nf < 3; ++nf) {
      const int col = n0 + wn * 48 + nf * 16 + m16;        // C/D col = lane&15
      if (col < 4096) {
        const float sc = (col < 2048) ? 0.125f : 1.f;      // pre-scale Q by SCALE
#pragma unroll
        for (int r = 0; r < 4; ++r)
          qk[(size_t)(rowb + r) * 4096 + col] = __float2bfloat16(acc[mf][nf][r] * sc);
      } else {
        const int vcol = col - 4096;
        const int ri = vcol >> 10, dfeat = vcol & 1023;
        const int b = rowb >> 11, seq = rowb & 2047;
        const size_t vrow = (size_t)(b * 2048 + (dfeat >> 6) * 128 + ri * 64 + (dfeat & 63));
        unsigned int lo = (unsigned)bfbits(acc[mf][nf][0]) | ((unsigned)bfbits(acc[mf][nf][1]) << 16);
        unsigned int hi = (unsigned)bfbits(acc[mf][nf][2]) | ((unsigned)bfbits(acc[mf][nf][3]) << 16);
        *(uint2*)(vt + vrow * 2048 + seq) = make_uint2(lo, hi);
      }
    }
  }
}

// ---------------------------------------------------------------- Output GEMM: 128x256, pipelined
// C = Acat(4096x2048) x Wo(2048x2048)^T, fp32 out + bias. Grid (32,8) = 256 blocks =
// exactly 1 round. 8 waves (2M x 4N), per-wave 64x64 = acc[4][4]. Same schedule as
// gemm_qkv: all tile-(t+2) staging at ph3 post-barrier (A 2 + B 4 = 6 loads), boundary
// vmcnt(0) drains exactly tile t+1's 6. LDS 96 KiB (sA 2x16K + sB 2x32K), 1 block/CU.
__global__ __launch_bounds__(512, 2) void gemm_out_k(const bf16_t* __restrict__ A,
                                                     const bf16_t* __restrict__ W,
                                                     const float* __restrict__ bor,
                                                     const float* __restrict__ boi,
                                                     float* __restrict__ out) {
  __shared__ __align__(16) bf16_t sA[2][128 * 64];  // 32 KB
  __shared__ __align__(16) bf16_t sB[2][256 * 64];  // 64 KB
  const int tid = threadIdx.x, lane = tid & 63, w = tid >> 6;
  const int wm = w >> 2, wn = w & 3;
  const int quad = lane >> 4, m16 = lane & 15;
  const int swz7 = m16 & 7;
  const int m0 = blockIdx.x * 128, n0 = blockIdx.y * 256;
  const int NT = 32;

  const int l3 = lane >> 3;
  const int gcol = (((lane & 7) ^ l3) * 8);

  f32x4 acc[4][4] = {};

  auto stageA = [&](int buf, int k0) {             // 128 rows, 2 instr/wave
#pragma unroll
    for (int i = 0; i < 2; ++i)
      gload_lds16(A + (size_t)(m0 + w * 16 + i * 8 + l3) * 2048 + k0 + gcol,
                  &sA[buf][(size_t)(w * 16 + i * 8) * 64] + lane * 8);
  };
  auto stageB = [&](int buf, int half, int k0) {   // one 128-row half, 2 instr/wave
#pragma unroll
    for (int i = 0; i < 2; ++i)
      gload_lds16(W + (size_t)(n0 + half * 128 + w * 16 + i * 8 + l3) * 2048 + k0 + gcol,
                  &sB[buf][(size_t)(half * 128 + w * 16 + i * 8) * 64] + lane * 8);
  };
  auto rdA = [&](const bf16_t* sAx, int mf, int kk) -> short8 {
    return *(const short8*)(sAx + (wm * 64 + mf * 16 + m16) * 64 +
                            ((kk * 4 + quad) ^ swz7) * 8);
  };
  auto rdB = [&](const bf16_t* sBx, int nf, int kk) -> short8 {
    return *(const short8*)(sBx + (wn * 64 + nf * 16 + m16) * 64 +
                            ((kk * 4 + quad) ^ swz7) * 8);
  };

  // prologue: stage tiles 0 and 1; drain tile 0 (leave tile 1's 6 in flight).
  stageA(0, 0);
  stageB(0, 0, 0); stageB(0, 1, 0);
  stageA(1, 64);
  stageB(1, 0, 64); stageB(1, 1, 64);
  asm volatile("s_waitcnt vmcnt(6)" ::: "memory");
  __builtin_amdgcn_s_barrier();

  short8 A0[2], A1[2], B0[4], B1[4];
#pragma unroll
  for (int i = 0; i < 2; ++i) A0[i] = rdA(sA[0], i, 0);
#pragma unroll
  for (int j = 0; j < 4; ++j) B0[j] = rdB(sB[0], j, 0);

  for (int t = 0; t < NT; ++t) {
    const int p = t & 1, q = p ^ 1;
    const bf16_t* sAp = sA[p];
    const bf16_t* sBp = sB[p];
    const bf16_t* sAq = sA[q];
    const bf16_t* sBq = sB[q];
    const bool stg = (t + 1 < NT);
    const bool stg2 = (t + 2 < NT);

    // ---- ph0: read A1(kk0); MFMA A0xB0 (acc rows 0-1)
#pragma unroll
    for (int i = 0; i < 2; ++i) A1[i] = rdA(sAp, 2 + i, 0);
    __builtin_amdgcn_s_setprio(1);
#pragma unroll
    for (int i = 0; i < 2; ++i)
#pragma unroll
      for (int j = 0; j < 4; ++j)
        acc[i][j] = __builtin_amdgcn_mfma_f32_16x16x32_bf16(A0[i], B0[j], acc[i][j], 0, 0, 0);
    __builtin_amdgcn_s_setprio(0);

    // ---- ph1: read A0(kk1), B1(kk1); MFMA A1xB0 (acc rows 2-3)
#pragma unroll
    for (int i = 0; i < 2; ++i) A0[i] = rdA(sAp, i, 1);
#pragma unroll
    for (int j = 0; j < 4; ++j) B1[j] = rdB(sBp, j, 1);
    __builtin_amdgcn_s_setprio(1);
#pragma unroll
    for (int i = 0; i < 2; ++i)
#pragma unroll
      for (int j = 0; j < 4; ++j)
        acc[2 + i][j] = __builtin_amdgcn_mfma_f32_16x16x32_bf16(A1[i], B0[j], acc[2 + i][j], 0, 0, 0);
    __builtin_amdgcn_s_setprio(0);

    // ---- ph2: read A1(kk1); MFMA A0xB1 (acc rows 0-1)
#pragma unroll
    for (int i = 0; i < 2; ++i) A1[i] = rdA(sAp, 2 + i, 1);
    __builtin_amdgcn_s_setprio(1);
#pragma unroll
    for (int i = 0; i < 2; ++i)
#pragma unroll
      for (int j = 0; j < 4; ++j)
        acc[i][j] = __builtin_amdgcn_mfma_f32_16x16x32_bf16(A0[i], B1[j], acc[i][j], 0, 0, 0);
    __builtin_amdgcn_s_setprio(0);

    // ---- tile boundary: exact drain of tile t+1's staging (issued ph3 of t-1)
    asm volatile("s_waitcnt vmcnt(0)" ::: "memory");
    __builtin_amdgcn_s_barrier();

    // ---- ph3: read A0,B0 of t+1 from q; stage ALL of tile t+2 -> p; MFMA A1xB1
    if (stg) {
#pragma unroll
      for (int i = 0; i < 2; ++i) A0[i] = rdA(sAq, i, 0);
#pragma unroll
      for (int j = 0; j < 4; ++j) B0[j] = rdB(sBq, j, 0);
    }
    if (stg2) {
      stageA(p, (t + 2) * 64);
      stageB(p, 0, (t + 2) * 64); stageB(p, 1, (t + 2) * 64);
    }
    __builtin_amdgcn_s_setprio(1);
#pragma unroll
    for (int i = 0; i < 2; ++i)
#pragma unroll
      for (int j = 0; j < 4; ++j)
        acc[2 + i][j] = __builtin_amdgcn_mfma_f32_16x16x32_bf16(A1[i], B1[j], acc[2 + i][j], 0, 0, 0);
    __builtin_amdgcn_s_setprio(0);
  }

  // epilogue: fp32 out + bias
#pragma unroll
  for (int mf = 0; mf < 4; ++mf) {
    const int rowb = m0 + wm * 64 + mf * 16 + quad * 4;
#pragma unroll
    for (int nf = 0; nf < 4; ++nf) {
      const int col = n0 + wn * 64 + nf * 16 + m16;
      float bias; float* op;
      if (col < 1024) { bias = bor[col]; op = out + col; }
      else            { bias = boi[col - 1024]; op = out + 4194304 + (col - 1024); }
#pragma unroll
      for (int r = 0; r < 4; ++r)
        op[(size_t)(rowb + r) * 1024] = acc[mf][nf][r] + bias;
    }
  }
}

// ---------------------------------------------------------------- flash attention
// grid (16, B*H), 512 threads = 8 waves. blockIdx.x remapped so consecutive blocks
// (likely CU-co-resident) pair complementary workloads: bx even -> x=bx/2, bx odd ->
// x=15-bx/2; every (even,odd) pair sums to 49 k-tiles. Pure bijection: output-identical.
// Waves 0-3 own 16 q-rows each of subtile A = x*64..; waves 4-7 own B = (31-x)*64.. .
// Shared staged K/V tile, joint k-loop, BK=64. Fixed-max softmax, ones-row-MFMA row sums.
__global__ __launch_bounds__(512, 4) void attn_k(const bf16_t* __restrict__ qk,
                                                 const bf16_t* __restrict__ vt,
                                                 bf16_t* __restrict__ acat) {
  __shared__ __align__(16) bf16_t sK[64 * 128];       // 16 KB
  __shared__ __align__(16) bf16_t sV[144 * 64];       // 18 KB (rows 128..143: ones/zeros)
  __shared__ __align__(16) bf16_t sP[8][16 * 72];     // 18 KB (one slab per wave)
  const int tid = threadIdx.x, lane = tid & 63, w = tid >> 6;
  const int wq = w & 3, sub = w >> 2;                 // sub 0 = subtile A, 1 = subtile B
  const int quad = lane >> 4, m16 = lane & 15;
  const int bx = blockIdx.x;
  const int x = (bx & 1) ? (15 - (bx >> 1)) : (bx >> 1);   // balanced pairing
  const int bh = blockIdx.y, b = bh >> 4, h = bh & 15;
  const size_t qkrow0 = (size_t)b * 2048;
  const int qA = x * 64, qB = (31 - x) * 64;
  const int nT = 32 - x;
  const int swz7 = m16 & 7;
  const int qbase = (sub ? qB : qA) + wq * 16;

  // preset sV rows 128..143: row 128 = ones, rest zeros (constant rows: swizzle-invariant)
  if (tid < 256) {
    const int rr = tid >> 4, cb = (tid & 15) * 4;
    const bf16_t v = __float2bfloat16(rr == 0 ? 1.f : 0.f);
#pragma unroll
    for (int i = 0; i < 4; ++i) sV[(128 + rr) * 64 + cb + i] = v;
  }

  // Q fragments for this wave's 16 rows (A-operand: m=lane&15, k=quad*8+j), d-chunks of 32
  short8 qf[4];
  {
    const bf16_t* qa = qk + (qkrow0 + qbase + m16) * 4096;
#pragma unroll
    for (int kk = 0; kk < 4; ++kk) {
      const int col = (kk >> 1) * 1024 + h * 64 + (kk & 1) * 32 + quad * 8;
      qf[kk] = *(const short8*)(qa + col);
    }
  }
  f32x4 o[9];
#pragma unroll
  for (int j = 0; j < 9; ++j) o[j] = (f32x4){0.f, 0.f, 0.f, 0.f};

  const int qrow = qbase + quad * 4;

  // staging geometry
  const int kl4 = lane >> 4, kl15 = lane & 15;   // K tile: 4 rows/instr (256 B rows)
  const int vl3 = lane >> 3;                     // V tile: 8 rows/instr (128 B rows)
  const int vg7 = ((lane & 7) ^ vl3) * 8;

  for (int t = 0; t < nT; ++t) {
    const int k0 = t * 64;
    __syncthreads();
    // stage K: 64 rows x 128 elem (Kr|Ki of head h); wave w covers rows w*8+i*4+kl4
#pragma unroll
    for (int i = 0; i < 2; ++i) {
      const int row = w * 8 + i * 4 + kl4;
      const int g = kl15 ^ (row & 7);            // low-3 XOR; bit3 of kl15 preserved
      const int col = 2048 + (g >> 3) * 1024 + h * 64 + (g & 7) * 8;
      gload_lds16(qk + (qkrow0 + k0 + row) * 4096 + col,
                  sK + (size_t)(w * 8 + i * 4) * 128 + lane * 8);
    }
    // stage V^T: 128 d-rows x 64 k; wave w covers rows w*16+i*8+vl3
#pragma unroll
    for (int i = 0; i < 2; ++i) {
      const int row = w * 16 + i * 8 + vl3;
      gload_lds16(vt + ((size_t)bh * 128 + row) * 2048 + k0 + vg7,
                  sV + (size_t)(w * 16 + i * 8) * 64 + lane * 8);
    }
    __syncthreads();

    const bool act = sub ? true : (t <= x);      // B-waves always active
    if (act) {
      const bool dg = sub ? (t == nT - 1) : (t == x);

      // ---- S = Qs·K^T (16 q-rows x 64 k)
      f32x4 sv[4];
#pragma unroll
      for (int jt = 0; jt < 4; ++jt) {
        f32x4 a = (f32x4){0.f, 0.f, 0.f, 0.f};
#pragma unroll
        for (int kk = 0; kk < 4; ++kk) {
          short8 kf = *(const short8*)(sK + (jt * 16 + m16) * 128 +
                                       ((kk * 4 + quad) ^ swz7) * 8);
          a = __builtin_amdgcn_mfma_f32_16x16x32_bf16(qf[kk], kf, a, 0, 0, 0);
        }
        sv[jt] = a;
      }

      // ---- fixed-max softmax: P = exp(S), C-layout -> A-layout via per-wave sP
      bf16_t* pw = sP[w];
#pragma unroll
      for (int jt = 0; jt < 4; ++jt)
#pragma unroll
        for (int r = 0; r < 4; ++r) {
          float s = sv[jt][r];
          if (dg && (k0 + jt * 16 + m16 > qrow + r)) s = -1e30f;
          pw[(quad * 4 + r) * 72 + jt * 16 + m16] = __float2bfloat16(__expf(s));
        }
      asm volatile("s_waitcnt lgkmcnt(0)" ::: "memory");  // own-wave P write->read

      // ---- O += P·V (j=8 = ones-row -> row sums l)
#pragma unroll
      for (int kc = 0; kc < 2; ++kc) {
        short8 p = *(const short8*)(pw + m16 * 72 + kc * 32 + quad * 8);
#pragma unroll
        for (int j = 0; j < 9; ++j) {
          short8 vf = *(const short8*)(sV + (j * 16 + m16) * 64 +
                                       ((kc * 4 + quad) ^ swz7) * 8);
          o[j] = __builtin_amdgcn_mfma_f32_16x16x32_bf16(p, vf, o[j], 0, 0, 0);
        }
      }
    }
  }

  // ---- epilogue: l broadcast from lane (quad*16), normalize, write [B,L,2048]=[out_r|out_i]
  float inv[4];
#pragma unroll
  for (int r = 0; r < 4; ++r)
    inv[r] = 1.f / __shfl(o[8][r], lane & 48);
#pragma unroll
  for (int j = 0; j < 8; ++j) {
    const int d = j * 16 + m16;
    const int col = (d < 64) ? (h * 64 + d) : (1024 + h * 64 + (d - 64));
#pragma unroll
    for (int r = 0; r < 4; ++r)
      acat[((size_t)b * 2048 + qrow + r) * 2048 + col] = __float2bfloat16(o[j][r] * inv[r]);
  }
}

// ---------------------------------------------------------------- launch
extern "C" void kernel_launch(void* const* d_in, const int* in_sizes, int n_in,
                              void* d_out, int out_size, void* d_ws, size_t ws_size,
                              hipStream_t stream) {
  const float* xr  = (const float*)d_in[0];
  const float* xi  = (const float*)d_in[1];
  const float* wqr = (const float*)d_in[2];
  const float* wqi = (const float*)d_in[3];
  const float* wkr = (const float*)d_in[4];
  const float* wki = (const float*)d_in[5];
  const float* wvr = (const float*)d_in[6];
  const float* wvi = (const float*)d_in[7];
  const float* wor = (const float*)d_in[8];
  const float* woi = (const float*)d_in[9];
  const float* bor = (const float*)d_in[10];
  const float* boi = (const float*)d_in[11];
  float* out = (float*)d_out;

  char* ws = (char*)d_ws;
  bf16_t* Xcat = (bf16_t*)(ws);                   // 4096x2048   16 MB
  bf16_t* Wqkv = (bf16_t*)(ws + 16777216ull);     // 6144x2048   24 MB
  bf16_t* QKb  = (bf16_t*)(ws + 41943040ull);     // 4096x4096   32 MB
  bf16_t* Vt   = (bf16_t*)(ws + 75497472ull);     // 4096x2048   16 MB (V transposed)
  bf16_t* Acat = (bf16_t*)(ws + 92274688ull);     // 4096x2048   16 MB
  bf16_t* Wo   = (bf16_t*)(ws + 109051904ull);    // 2048x2048    8 MB

  pack_x_k<<<2048, 256, 0, stream>>>(xr, xi, Xcat);
  pack_wqkv_k<<<2048, 256, 0, stream>>>(wqr, wqi, wkr, wki, wvr, wvi, Wqkv);
  pack_wo_k<<<1024, 256, 0, stream>>>(wor, woi, Wo);
  gemm_qkv_k<<<dim3(16, 32), 512, 0, stream>>>(Xcat, Wqkv, QKb, Vt);
  attn_k<<<dim3(16, 32), 512, 0, stream>>>(QKb, Vt, Acat);
  gemm_out_k<<<dim3(32, 8), 512, 0, stream>>>(Acat, Wo, bor, boi, out);
}